// Round 7
// baseline (385.781 us; speedup 1.0000x reference)
//
#include <hip/hip_runtime.h>
#include <math.h>

// AdaptedMixer — Round 7: scan kernels rebuilt for latency:
//  - NCH=64 (CHS=32): 3072 blocks per scan phase (12/CU).
//  - k5a/k5c stage dt/h (interleaved) + g into LDS via burst coalesced loads;
//    t-loop reads LDS + L2-resident wave-uniform B/C. 1 chain/thread, 4 n-lanes.
//  - CIn aliases PArr (read-before-write in k5b) so summaries fit dead hidden buf.
// B=2 S=2048 Dm=768 I=1536 N=16 R=48 K=4.  M = B*S = 4096.

static constexpr int S_LEN  = 2048;
static constexpr int DMODEL = 768;
static constexpr int ICH    = 1536;
static constexpr int NST    = 16;
static constexpr int MROWS  = 4096;   // B*S
static constexpr int NCH    = 64;     // scan chunks
static constexpr int CHS    = 32;     // steps per chunk

typedef _Float16 f16;
typedef f16 f16x8 __attribute__((ext_vector_type(8)));
typedef f16 f16x4 __attribute__((ext_vector_type(4)));
typedef float f32x4 __attribute__((ext_vector_type(4)));

typedef __attribute__((address_space(3))) void lds_void;
typedef const __attribute__((address_space(1))) void glb_void;

__device__ __forceinline__ void glds16(f16* l, const f16* g) {
    __builtin_amdgcn_global_load_lds((glb_void*)g, (lds_void*)l, 16, 0, 0);
}

__device__ __forceinline__ float silu_f(float x) {
    return x / (1.0f + __expf(-x));
}

// ---------------- cvt: fp32 -> fp16, 4 elems/thread
__global__ __launch_bounds__(256) void cvt_h(
    const float* __restrict__ s, f16* __restrict__ d)
{
    int i = (blockIdx.x * 256 + threadIdx.x) * 4;
    float4 v = *(const float4*)(s + i);
    f16x4 o = { (f16)v.x, (f16)v.y, (f16)v.z, (f16)v.w };
    *(f16x4*)(d + i) = o;
}

// ---------------- K1: in_proj fp16 MFMA GEMM [4096,768] @ [3072,768]^T, async staging
__global__ __launch_bounds__(256) void k1m(
    const f16* __restrict__ Xh,    // [4096][768]
    const f16* __restrict__ Wh,    // [3072][768]
    float* __restrict__ hidden,    // [M][I]
    float* __restrict__ sgate)     // [M][I] (silu applied)
{
    __shared__ __align__(16) f16 As[128 * 32];
    __shared__ __align__(16) f16 Bs[128 * 32];
    const int tid = threadIdx.x;
    const int lane = tid & 63, wave = tid >> 6;
    const int quad = lane >> 4, l16 = lane & 15;
    const int wm = wave & 1, wn = wave >> 1;
    const int m0 = blockIdx.x * 128, n0 = blockIdx.y * 128;
    const int l_row = lane >> 2, l_c8 = (lane & 3) * 8;

    const f16* Ag = Xh + (size_t)(m0 + wave * 16 + l_row) * 768 + l_c8;
    const f16* Bg = Wh + (size_t)(n0 + wave * 16 + l_row) * 768 + l_c8;
    f16* As0 = As + (wave * 16) * 32;
    f16* As1 = As + (64 + wave * 16) * 32;
    f16* Bs0 = Bs + (wave * 16) * 32;
    f16* Bs1 = Bs + (64 + wave * 16) * 32;

    f32x4 acc[4][4] = {};
    for (int k0 = 0; k0 < 768; k0 += 32) {
        __syncthreads();
        glds16(As0, Ag + k0);
        glds16(As1, Ag + (size_t)64 * 768 + k0);
        glds16(Bs0, Bg + k0);
        glds16(Bs1, Bg + (size_t)64 * 768 + k0);
        __syncthreads();
        f16x8 af[4], bf[4];
        #pragma unroll
        for (int mi = 0; mi < 4; ++mi)
            af[mi] = *(const f16x8*)&As[(wm * 64 + mi * 16 + l16) * 32 + quad * 8];
        #pragma unroll
        for (int ni = 0; ni < 4; ++ni)
            bf[ni] = *(const f16x8*)&Bs[(wn * 64 + ni * 16 + l16) * 32 + quad * 8];
        #pragma unroll
        for (int mi = 0; mi < 4; ++mi)
            #pragma unroll
            for (int ni = 0; ni < 4; ++ni)
                acc[mi][ni] = __builtin_amdgcn_mfma_f32_16x16x32_f16(
                    af[mi], bf[ni], acc[mi][ni], 0, 0, 0);
    }
    const bool isGate = (n0 >= ICH);
    float* outp = isGate ? sgate : hidden;
    const int e0 = (isGate ? (n0 - ICH) : n0) + wn * 64 + l16;
    #pragma unroll
    for (int mi = 0; mi < 4; ++mi) {
        #pragma unroll
        for (int ni = 0; ni < 4; ++ni) {
            #pragma unroll
            for (int r = 0; r < 4; ++r) {
                int m = m0 + wm * 64 + mi * 16 + quad * 4 + r;
                int e = e0 + ni * 16;
                float v = acc[mi][ni][r];
                if (isGate) v = silu_f(v);
                outp[(size_t)m * ICH + e] = v;
            }
        }
    }
}

// ---------------- K2: causal depthwise conv (K=4) + bias + silu, [M][I] layout
__global__ __launch_bounds__(256) void k2_conv(
    const float* __restrict__ hidden,  // [M][I]
    const float* __restrict__ conv_w,  // [I][4]
    const float* __restrict__ conv_b,  // [I]
    float* __restrict__ h)             // [M][I]
{
    int idx = blockIdx.x * 256 + threadIdx.x;      // over M * (I/4)
    int i4 = idx % 384;
    int m  = idx / 384;
    int s  = m & (S_LEN - 1);
    const float* base = hidden + (size_t)m * ICH + i4 * 4;
    const int c0 = i4 * 4;
    float4 wa = *(const float4*)(conv_w + (c0 + 0) * 4);
    float4 wb = *(const float4*)(conv_w + (c0 + 1) * 4);
    float4 wc = *(const float4*)(conv_w + (c0 + 2) * 4);
    float4 wd = *(const float4*)(conv_w + (c0 + 3) * 4);
    float4 bv = *(const float4*)(conv_b + c0);
    float4 z = {0.f, 0.f, 0.f, 0.f};
    float4 x0 = *(const float4*)(base);
    float4 x1 = (s >= 1) ? *(const float4*)(base - ICH)     : z;
    float4 x2 = (s >= 2) ? *(const float4*)(base - 2 * ICH) : z;
    float4 x3 = (s >= 3) ? *(const float4*)(base - 3 * ICH) : z;
    float4 r;
    r.x = bv.x + wa.x * x3.x + wa.y * x2.x + wa.z * x1.x + wa.w * x0.x;
    r.y = bv.y + wb.x * x3.y + wb.y * x2.y + wb.z * x1.y + wb.w * x0.y;
    r.z = bv.z + wc.x * x3.z + wc.y * x2.z + wc.z * x1.z + wc.w * x0.z;
    r.w = bv.w + wd.x * x3.w + wd.y * x2.w + wd.z * x1.w + wd.w * x0.w;
    r.x = silu_f(r.x); r.y = silu_f(r.y); r.z = silu_f(r.z); r.w = silu_f(r.w);
    *(float4*)(h + (size_t)m * ICH + i4 * 4) = r;
}

// ---------------- K3: x_proj GEMM: ssmp[m][e] += h[m][:] . xw[e][:], K-split x4 atomics
__global__ __launch_bounds__(256) void k3_xproj(
    const float* __restrict__ h,   // [M][I]
    const float* __restrict__ xw,  // [80][I]
    float* __restrict__ ssmp)      // [M][80], pre-zeroed
{
    __shared__ float4 As[64][5];   // [m][k4]
    __shared__ float4 Bs[80][5];   // [e][k4]
    const int tid = threadIdx.x;
    const int tm = tid >> 4;       // m group 0..15
    const int te = tid & 15;       // e lane 0..15
    const int m0 = blockIdx.x * 64;
    const int k_beg = blockIdx.y * 384;
    const int lrow = tid >> 2, lc4 = tid & 3;
    float4 acc[4][5] = {};
    for (int k0 = k_beg; k0 < k_beg + 384; k0 += 16) {
        As[lrow][lc4] = *(const float4*)(h + (size_t)(m0 + lrow) * ICH + k0 + lc4 * 4);
        for (int t = tid; t < 320; t += 256)
            Bs[t >> 2][t & 3] = *(const float4*)(xw + (size_t)(t >> 2) * ICH + k0 + (t & 3) * 4);
        __syncthreads();
        #pragma unroll
        for (int kk4 = 0; kk4 < 4; ++kk4) {
            float4 a[4], b[5];
            #pragma unroll
            for (int i = 0; i < 4; ++i) a[i] = As[tm + 16 * i][kk4];
            #pragma unroll
            for (int j = 0; j < 5; ++j) b[j] = Bs[te + 16 * j][kk4];
            #pragma unroll
            for (int i = 0; i < 4; ++i)
                #pragma unroll
                for (int j = 0; j < 5; ++j) {
                    acc[i][j].x += a[i].x * b[j].x; acc[i][j].y += a[i].y * b[j].y;
                    acc[i][j].z += a[i].z * b[j].z; acc[i][j].w += a[i].w * b[j].w;
                }
        }
        __syncthreads();
    }
    #pragma unroll
    for (int i = 0; i < 4; ++i) {
        int m = m0 + tm + 16 * i;
        #pragma unroll
        for (int j = 0; j < 5; ++j) {
            float v = acc[i][j].x + acc[i][j].y + acc[i][j].z + acc[i][j].w;
            atomicAdd(ssmp + (size_t)m * 80 + te + 16 * j, v);
        }
    }
}

// ---------------- K4: dt = softplus(ts @ dtw^T + b) via fp16 MFMA, K=48 padded to 64.
__global__ __launch_bounds__(256) void k4m(
    const float* __restrict__ ssmp,   // [M][80] (ts = cols 0..47)
    const float* __restrict__ dtw,    // [I][48]
    const float* __restrict__ dtb,    // [I]
    const float* __restrict__ alpha,  // [I]
    float* __restrict__ dt)           // [M][I]
{
    __shared__ __align__(16) f16 As[128 * 72];   // [row][72] (64 K + 8 pad)
    __shared__ __align__(16) f16 Bs[128 * 72];
    const int tid = threadIdx.x;
    const int lane = tid & 63, wave = tid >> 6;
    const int quad = lane >> 4, l16 = lane & 15;
    const int wm = wave & 1, wn = wave >> 1;
    const int m0 = blockIdx.x * 128, n0 = blockIdx.y * 128;
    const int srow = tid >> 1;          // 0..127
    const int shalf = tid & 1;          // 0..1 -> cols [0,24) or [24,48)

    {   // stage A (ts) and B (dtw), cvt to fp16, zero-pad cols 48..63
        const float* sa = ssmp + (size_t)(m0 + srow) * 80 + shalf * 24;
        const float* sb = dtw + (size_t)(n0 + srow) * 48 + shalf * 24;
        f16* da = &As[srow * 72 + shalf * 24];
        f16* db = &Bs[srow * 72 + shalf * 24];
        #pragma unroll
        for (int j = 0; j < 6; ++j) {
            float4 va = *(const float4*)(sa + 4 * j);
            float4 vb = *(const float4*)(sb + 4 * j);
            f16x4 oa = { (f16)va.x, (f16)va.y, (f16)va.z, (f16)va.w };
            f16x4 ob = { (f16)vb.x, (f16)vb.y, (f16)vb.z, (f16)vb.w };
            *(f16x4*)(da + 4 * j) = oa;
            *(f16x4*)(db + 4 * j) = ob;
        }
        if (shalf) {
            f16x8 z = {};
            *(f16x8*)&As[srow * 72 + 48] = z;
            *(f16x8*)&As[srow * 72 + 56] = z;
            *(f16x8*)&Bs[srow * 72 + 48] = z;
            *(f16x8*)&Bs[srow * 72 + 56] = z;
        }
    }
    __syncthreads();

    f32x4 acc[4][4] = {};
    #pragma unroll
    for (int ks = 0; ks < 2; ++ks) {
        f16x8 af[4], bf[4];
        #pragma unroll
        for (int mi = 0; mi < 4; ++mi)
            af[mi] = *(const f16x8*)&As[(wm * 64 + mi * 16 + l16) * 72 + ks * 32 + quad * 8];
        #pragma unroll
        for (int ni = 0; ni < 4; ++ni)
            bf[ni] = *(const f16x8*)&Bs[(wn * 64 + ni * 16 + l16) * 72 + ks * 32 + quad * 8];
        #pragma unroll
        for (int mi = 0; mi < 4; ++mi)
            #pragma unroll
            for (int ni = 0; ni < 4; ++ni)
                acc[mi][ni] = __builtin_amdgcn_mfma_f32_16x16x32_f16(
                    af[mi], bf[ni], acc[mi][ni], 0, 0, 0);
    }

    #pragma unroll
    for (int ni = 0; ni < 4; ++ni) {
        int e = n0 + wn * 64 + ni * 16 + l16;
        float bias = dtb[e];
        float al = alpha[e];
        #pragma unroll
        for (int mi = 0; mi < 4; ++mi) {
            #pragma unroll
            for (int r = 0; r < 4; ++r) {
                int m = m0 + wm * 64 + mi * 16 + quad * 4 + r;
                float x = acc[mi][ni][r] + bias;
                float sp = (x > 20.0f) ? x : __logf(1.0f + __expf(x));
                if ((m & (S_LEN - 1)) == S_LEN - 1) sp *= al;
                dt[(size_t)m * ICH + e] = sp;
            }
        }
    }
}

// ---------------- K5a: scan phase A — per-chunk summary, LDS-staged dt/h.
// grid (I/64, NCH, B), block 256 = 64 chains x 4 n-lanes
__global__ __launch_bounds__(256) void k5a_chunk(
    const float* __restrict__ dt,    // [M][I]
    const float* __restrict__ h,     // [M][I]
    const float* __restrict__ ssmp,  // [M][80]: B cols 48..63
    const float* __restrict__ A_log, // [I][16]
    float* __restrict__ PArr,        // [B*I*16][NCH]
    float* __restrict__ SfArr)       // [B*I*16][NCH]
{
    __shared__ float2 dh[CHS * 64];  // [t][ii] = (dt, h)
    const int tid = threadIdx.x;
    const int n4 = tid & 3;
    const int il = tid >> 2;         // 0..63
    const int i0 = blockIdx.x * 64;
    const int i = i0 + il;
    const int c = blockIdx.y;
    const int b = blockIdx.z;
    const int s0 = c * CHS;
    const size_t row0 = (size_t)(b * S_LEN + s0) * ICH + i0;

    #pragma unroll
    for (int k = 0; k < (CHS * 64) / 256; ++k) {
        int idx = tid + k * 256;
        int t = idx >> 6, ii = idx & 63;
        float dv = dt[row0 + (size_t)t * ICH + ii];
        float hv = h[row0 + (size_t)t * ICH + ii];
        dh[idx] = make_float2(dv, hv);
    }

    const float L2E = 1.44269504088896f;
    float4 alv = *(const float4*)(A_log + i * NST + n4 * 4);
    float A[4] = { -expf(alv.x) * L2E, -expf(alv.y) * L2E,
                   -expf(alv.z) * L2E, -expf(alv.w) * L2E };
    float st[4] = {};
    float cdt = 0.f;
    const float* Bp = ssmp + (size_t)(b * S_LEN + s0) * 80 + 48 + n4 * 4;
    __syncthreads();
    #pragma unroll 4
    for (int t = 0; t < CHS; ++t) {
        float2 dhv = dh[t * 64 + il];
        float4 Bv = *(const float4*)(Bp + (size_t)t * 80);
        cdt += dhv.x;
        float x = dhv.x * dhv.y;
        #pragma unroll
        for (int j = 0; j < 4; ++j) {
            float dA = exp2f(A[j] * dhv.x);
            st[j] = fmaf(dA, st[j], x * (&Bv.x)[j]);
        }
    }
    size_t base = ((size_t)(b * ICH + i) * NST + n4 * 4) * NCH + c;
    #pragma unroll
    for (int j = 0; j < 4; ++j) {
        PArr[base + (size_t)j * NCH]  = exp2f(A[j] * cdt);   // telescoped prod dA
        SfArr[base + (size_t)j * NCH] = st[j];
    }
}

// ---------------- K5b: combine chunk summaries into carry-in per chunk.
// NOTE: CIn aliases PArr — read P/Sf before writing CIn at the same index.
__global__ __launch_bounds__(256) void k5b_carry(
    const float* PArr,
    const float* __restrict__ SfArr,
    float* CIn)
{
    int idx = blockIdx.x * 256 + threadIdx.x;   // over B*I*16 = 49152
    size_t base = (size_t)idx * NCH;
    float carry = 0.f;
    #pragma unroll 8
    for (int c = 0; c < NCH; ++c) {
        float p = PArr[base + c];
        float s = SfArr[base + c];
        CIn[base + c] = carry;
        carry = fmaf(p, carry, s);
    }
}

// ---------------- K5c: replay chunk with carry-in, emit y fp16; LDS-staged dt/h/g
__global__ __launch_bounds__(256) void k5c_emit(
    const float* __restrict__ dt,    // [M][I]
    const float* __restrict__ h,     // [M][I]
    const float* __restrict__ sgate, // [M][I]
    const float* __restrict__ ssmp,  // [M][80]: B 48..63, C 64..79
    const float* __restrict__ A_log, // [I][16]
    const float* __restrict__ Dp,    // [I]
    const float* __restrict__ fg,    // [I]
    const float* __restrict__ CIn,   // [B*I*16][NCH]
    f16* __restrict__ yh)            // [M][I] fp16
{
    __shared__ float2 dh[CHS * 64];
    __shared__ float gb[CHS * 64];
    const int tid = threadIdx.x;
    const int n4 = tid & 3;
    const int il = tid >> 2;
    const int i0 = blockIdx.x * 64;
    const int i = i0 + il;
    const int c = blockIdx.y;
    const int b = blockIdx.z;
    const int s0 = c * CHS;
    const size_t row0 = (size_t)(b * S_LEN + s0) * ICH + i0;

    #pragma unroll
    for (int k = 0; k < (CHS * 64) / 256; ++k) {
        int idx = tid + k * 256;
        int t = idx >> 6, ii = idx & 63;
        float dv = dt[row0 + (size_t)t * ICH + ii];
        float hv = h[row0 + (size_t)t * ICH + ii];
        float gv = sgate[row0 + (size_t)t * ICH + ii];
        dh[idx] = make_float2(dv, hv);
        gb[idx] = gv;
    }

    const float L2E = 1.44269504088896f;
    float4 alv = *(const float4*)(A_log + i * NST + n4 * 4);
    float A[4] = { -expf(alv.x) * L2E, -expf(alv.y) * L2E,
                   -expf(alv.z) * L2E, -expf(alv.w) * L2E };
    const float Dv = Dp[i];
    const float fgv = fg[i];
    size_t cbase = ((size_t)(b * ICH + i) * NST + n4 * 4) * NCH + c;
    float st[4];
    #pragma unroll
    for (int j = 0; j < 4; ++j) st[j] = CIn[cbase + (size_t)j * NCH];
    const float* Bp = ssmp + (size_t)(b * S_LEN + s0) * 80 + 48 + n4 * 4;
    const float* Cp = Bp + 16;
    f16* yout = yh + row0 + il;
    const bool last_chunk = (c == NCH - 1);
    __syncthreads();
    #pragma unroll 4
    for (int t = 0; t < CHS; ++t) {
        float2 dhv = dh[t * 64 + il];
        float4 Bv = *(const float4*)(Bp + (size_t)t * 80);
        float4 Cv = *(const float4*)(Cp + (size_t)t * 80);
        float x = dhv.x * dhv.y;
        float yp = 0.f;
        #pragma unroll
        for (int j = 0; j < 4; ++j) {
            float dA = exp2f(A[j] * dhv.x);
            st[j] = fmaf(dA, st[j], x * (&Bv.x)[j]);
            yp = fmaf(st[j], (&Cv.x)[j], yp);
        }
        yp += __shfl_xor(yp, 1, 4);
        yp += __shfl_xor(yp, 2, 4);
        if (n4 == 0) {
            float yv = fmaf(dhv.y, Dv, yp) * gb[t * 64 + il];
            if (last_chunk && t == CHS - 1) yv *= fgv;
            yout[(size_t)t * ICH] = (f16)yv;
        }
    }
}

// ---------------- K6: out_proj fp16 MFMA GEMM [4096,1536] @ [768,1536]^T, async staging
__global__ __launch_bounds__(256) void k6m(
    const f16* __restrict__ Yh,    // [4096][1536]
    const f16* __restrict__ Wh,    // [768][1536]
    float* __restrict__ out)       // [M][768]
{
    __shared__ __align__(16) f16 As[128 * 32];
    __shared__ __align__(16) f16 Bs[128 * 32];
    const int tid = threadIdx.x;
    const int lane = tid & 63, wave = tid >> 6;
    const int quad = lane >> 4, l16 = lane & 15;
    const int wm = wave & 1, wn = wave >> 1;
    const int m0 = blockIdx.x * 128, n0 = blockIdx.y * 128;
    const int l_row = lane >> 2, l_c8 = (lane & 3) * 8;

    const f16* Ag = Yh + (size_t)(m0 + wave * 16 + l_row) * ICH + l_c8;
    const f16* Bg = Wh + (size_t)(n0 + wave * 16 + l_row) * ICH + l_c8;
    f16* As0 = As + (wave * 16) * 32;
    f16* As1 = As + (64 + wave * 16) * 32;
    f16* Bs0 = Bs + (wave * 16) * 32;
    f16* Bs1 = Bs + (64 + wave * 16) * 32;

    f32x4 acc[4][4] = {};
    for (int k0 = 0; k0 < ICH; k0 += 32) {
        __syncthreads();
        glds16(As0, Ag + k0);
        glds16(As1, Ag + (size_t)64 * ICH + k0);
        glds16(Bs0, Bg + k0);
        glds16(Bs1, Bg + (size_t)64 * ICH + k0);
        __syncthreads();
        f16x8 af[4], bf[4];
        #pragma unroll
        for (int mi = 0; mi < 4; ++mi)
            af[mi] = *(const f16x8*)&As[(wm * 64 + mi * 16 + l16) * 32 + quad * 8];
        #pragma unroll
        for (int ni = 0; ni < 4; ++ni)
            bf[ni] = *(const f16x8*)&Bs[(wn * 64 + ni * 16 + l16) * 32 + quad * 8];
        #pragma unroll
        for (int mi = 0; mi < 4; ++mi)
            #pragma unroll
            for (int ni = 0; ni < 4; ++ni)
                acc[mi][ni] = __builtin_amdgcn_mfma_f32_16x16x32_f16(
                    af[mi], bf[ni], acc[mi][ni], 0, 0, 0);
    }
    #pragma unroll
    for (int mi = 0; mi < 4; ++mi) {
        #pragma unroll
        for (int ni = 0; ni < 4; ++ni) {
            #pragma unroll
            for (int r = 0; r < 4; ++r) {
                int m = m0 + wm * 64 + mi * 16 + quad * 4 + r;
                int d = n0 + wn * 64 + ni * 16 + l16;
                out[(size_t)m * DMODEL + d] = acc[mi][ni][r];
            }
        }
    }
}

extern "C" void kernel_launch(void* const* d_in, const int* in_sizes, int n_in,
                              void* d_out, int out_size, void* d_ws, size_t ws_size,
                              hipStream_t stream) {
    const float* X     = (const float*)d_in[0];
    const float* W1    = (const float*)d_in[1];
    const float* CW    = (const float*)d_in[2];
    const float* CB    = (const float*)d_in[3];
    const float* XW    = (const float*)d_in[4];
    const float* DTW   = (const float*)d_in[5];
    const float* DTB   = (const float*)d_in[6];
    const float* ALOG  = (const float*)d_in[7];
    const float* DD    = (const float*)d_in[8];
    const float* OW    = (const float*)d_in[9];
    const float* ALPHA = (const float*)d_in[10];
    const float* FG    = (const float*)d_in[11];
    float* out = (float*)d_out;

    float* ws = (float*)d_ws;
    const size_t NBI = (size_t)MROWS * ICH;        // 6,291,456
    float* hidden = ws;
    float* sgate  = hidden + NBI;
    float* hbuf   = sgate + NBI;
    float* dtbuf  = hbuf + NBI;
    float* ssmp   = dtbuf + NBI;                   // 4096*80
    // halves region R1: [Xh | W1h] before k5c, reused as yh after
    f16* R1  = (f16*)(ssmp + (size_t)MROWS * 80);
    f16* Xh  = R1;                                  // 4096*768
    f16* W1h = R1 + (size_t)MROWS * DMODEL;         // 3072*768
    f16* yh  = R1;                                  // 4096*1536 (overlays Xh|W1h)
    f16* OWh = R1 + NBI;                            // 768*1536, lives until k6
    // scan chunk summaries overlay dead hidden buffer:
    // P and Sf each B*I*16*NCH = 3,145,728 floats; CIn aliases PArr (k5b is safe).
    const size_t SEG = (size_t)2 * ICH * NST * NCH;  // 3,145,728
    float* PArr = hidden;
    float* SfA  = hidden + SEG;
    float* CIn  = PArr;

    hipMemsetAsync(ssmp, 0, (size_t)MROWS * 80 * sizeof(float), stream);
    cvt_h<<<dim3(3072), 256, 0, stream>>>(X,  Xh);
    cvt_h<<<dim3(2304), 256, 0, stream>>>(W1, W1h);
    cvt_h<<<dim3(1152), 256, 0, stream>>>(OW, OWh);
    k1m<<<dim3(32, 24), 256, 0, stream>>>(Xh, W1h, hidden, sgate);
    k2_conv<<<dim3((MROWS * 384) / 256), 256, 0, stream>>>(hidden, CW, CB, hbuf);
    k3_xproj<<<dim3(64, 4), 256, 0, stream>>>(hbuf, XW, ssmp);
    k4m<<<dim3(32, 12), 256, 0, stream>>>(ssmp, DTW, DTB, ALPHA, dtbuf);
    k5a_chunk<<<dim3(24, NCH, 2), 256, 0, stream>>>(dtbuf, hbuf, ssmp, ALOG, PArr, SfA);
    k5b_carry<<<dim3(192), 256, 0, stream>>>(PArr, SfA, CIn);
    k5c_emit<<<dim3(24, NCH, 2), 256, 0, stream>>>(dtbuf, hbuf, sgate, ssmp, ALOG, DD, FG, CIn, yh);
    k6m<<<dim3(32, 6), 256, 0, stream>>>(yh, OWh, out);
}

// Round 9
// 322.651 us; speedup vs baseline: 1.1957x; 1.1957x over previous
//
#include <hip/hip_runtime.h>
#include <math.h>

// AdaptedMixer — Round 8 (resubmit; R8 bench was a container failure):
//  - P/Sf/CIn transposed to [c][b*i*n]: k5a float4 coalesced stores, k5c float4 CIn read.
//  - k5a/k5c stage B/C rows into LDS (one coalesced sweep); t-loop = pure LDS+VALU.
//  - single cvt3 kernel for the three fp32->fp16 conversions.
// B=2 S=2048 Dm=768 I=1536 N=16 R=48 K=4.  M = B*S = 4096.

static constexpr int S_LEN  = 2048;
static constexpr int DMODEL = 768;
static constexpr int ICH    = 1536;
static constexpr int NST    = 16;
static constexpr int MROWS  = 4096;   // B*S
static constexpr int NCH    = 64;     // scan chunks
static constexpr int CHS    = 32;     // steps per chunk
static constexpr int CSTR   = 2 * ICH * NST;   // 49152: per-chunk summary stride

typedef _Float16 f16;
typedef f16 f16x8 __attribute__((ext_vector_type(8)));
typedef f16 f16x4 __attribute__((ext_vector_type(4)));
typedef float f32x4 __attribute__((ext_vector_type(4)));

typedef __attribute__((address_space(3))) void lds_void;
typedef const __attribute__((address_space(1))) void glb_void;

__device__ __forceinline__ void glds16(f16* l, const f16* g) {
    __builtin_amdgcn_global_load_lds((glb_void*)g, (lds_void*)l, 16, 0, 0);
}

__device__ __forceinline__ float silu_f(float x) {
    return x / (1.0f + __expf(-x));
}

// ---------------- cvt3: three fp32->fp16 conversions in one launch
__global__ __launch_bounds__(256) void cvt3(
    const float* __restrict__ s0, f16* __restrict__ d0, int n0,
    const float* __restrict__ s1, f16* __restrict__ d1, int n1,
    const float* __restrict__ s2, f16* __restrict__ d2)
{
    int i = (blockIdx.x * 256 + threadIdx.x) * 4;
    const float* s; f16* d;
    if (i < n0)            { s = s0 + i;            d = d0 + i; }
    else if (i < n0 + n1)  { s = s1 + (i - n0);     d = d1 + (i - n0); }
    else                   { s = s2 + (i - n0 - n1); d = d2 + (i - n0 - n1); }
    float4 v = *(const float4*)s;
    f16x4 o = { (f16)v.x, (f16)v.y, (f16)v.z, (f16)v.w };
    *(f16x4*)d = o;
}

// ---------------- K1: in_proj fp16 MFMA GEMM [4096,768] @ [3072,768]^T, async staging
__global__ __launch_bounds__(256) void k1m(
    const f16* __restrict__ Xh,    // [4096][768]
    const f16* __restrict__ Wh,    // [3072][768]
    float* __restrict__ hidden,    // [M][I]
    float* __restrict__ sgate)     // [M][I] (silu applied)
{
    __shared__ __align__(16) f16 As[128 * 32];
    __shared__ __align__(16) f16 Bs[128 * 32];
    const int tid = threadIdx.x;
    const int lane = tid & 63, wave = tid >> 6;
    const int quad = lane >> 4, l16 = lane & 15;
    const int wm = wave & 1, wn = wave >> 1;
    const int m0 = blockIdx.x * 128, n0 = blockIdx.y * 128;
    const int l_row = lane >> 2, l_c8 = (lane & 3) * 8;

    const f16* Ag = Xh + (size_t)(m0 + wave * 16 + l_row) * 768 + l_c8;
    const f16* Bg = Wh + (size_t)(n0 + wave * 16 + l_row) * 768 + l_c8;
    f16* As0 = As + (wave * 16) * 32;
    f16* As1 = As + (64 + wave * 16) * 32;
    f16* Bs0 = Bs + (wave * 16) * 32;
    f16* Bs1 = Bs + (64 + wave * 16) * 32;

    f32x4 acc[4][4] = {};
    for (int k0 = 0; k0 < 768; k0 += 32) {
        __syncthreads();
        glds16(As0, Ag + k0);
        glds16(As1, Ag + (size_t)64 * 768 + k0);
        glds16(Bs0, Bg + k0);
        glds16(Bs1, Bg + (size_t)64 * 768 + k0);
        __syncthreads();
        f16x8 af[4], bf[4];
        #pragma unroll
        for (int mi = 0; mi < 4; ++mi)
            af[mi] = *(const f16x8*)&As[(wm * 64 + mi * 16 + l16) * 32 + quad * 8];
        #pragma unroll
        for (int ni = 0; ni < 4; ++ni)
            bf[ni] = *(const f16x8*)&Bs[(wn * 64 + ni * 16 + l16) * 32 + quad * 8];
        #pragma unroll
        for (int mi = 0; mi < 4; ++mi)
            #pragma unroll
            for (int ni = 0; ni < 4; ++ni)
                acc[mi][ni] = __builtin_amdgcn_mfma_f32_16x16x32_f16(
                    af[mi], bf[ni], acc[mi][ni], 0, 0, 0);
    }
    const bool isGate = (n0 >= ICH);
    float* outp = isGate ? sgate : hidden;
    const int e0 = (isGate ? (n0 - ICH) : n0) + wn * 64 + l16;
    #pragma unroll
    for (int mi = 0; mi < 4; ++mi) {
        #pragma unroll
        for (int ni = 0; ni < 4; ++ni) {
            #pragma unroll
            for (int r = 0; r < 4; ++r) {
                int m = m0 + wm * 64 + mi * 16 + quad * 4 + r;
                int e = e0 + ni * 16;
                float v = acc[mi][ni][r];
                if (isGate) v = silu_f(v);
                outp[(size_t)m * ICH + e] = v;
            }
        }
    }
}

// ---------------- K2: causal depthwise conv (K=4) + bias + silu, [M][I] layout
__global__ __launch_bounds__(256) void k2_conv(
    const float* __restrict__ hidden,  // [M][I]
    const float* __restrict__ conv_w,  // [I][4]
    const float* __restrict__ conv_b,  // [I]
    float* __restrict__ h)             // [M][I]
{
    int idx = blockIdx.x * 256 + threadIdx.x;      // over M * (I/4)
    int i4 = idx % 384;
    int m  = idx / 384;
    int s  = m & (S_LEN - 1);
    const float* base = hidden + (size_t)m * ICH + i4 * 4;
    const int c0 = i4 * 4;
    float4 wa = *(const float4*)(conv_w + (c0 + 0) * 4);
    float4 wb = *(const float4*)(conv_w + (c0 + 1) * 4);
    float4 wc = *(const float4*)(conv_w + (c0 + 2) * 4);
    float4 wd = *(const float4*)(conv_w + (c0 + 3) * 4);
    float4 bv = *(const float4*)(conv_b + c0);
    float4 z = {0.f, 0.f, 0.f, 0.f};
    float4 x0 = *(const float4*)(base);
    float4 x1 = (s >= 1) ? *(const float4*)(base - ICH)     : z;
    float4 x2 = (s >= 2) ? *(const float4*)(base - 2 * ICH) : z;
    float4 x3 = (s >= 3) ? *(const float4*)(base - 3 * ICH) : z;
    float4 r;
    r.x = bv.x + wa.x * x3.x + wa.y * x2.x + wa.z * x1.x + wa.w * x0.x;
    r.y = bv.y + wb.x * x3.y + wb.y * x2.y + wb.z * x1.y + wb.w * x0.y;
    r.z = bv.z + wc.x * x3.z + wc.y * x2.z + wc.z * x1.z + wc.w * x0.z;
    r.w = bv.w + wd.x * x3.w + wd.y * x2.w + wd.z * x1.w + wd.w * x0.w;
    r.x = silu_f(r.x); r.y = silu_f(r.y); r.z = silu_f(r.z); r.w = silu_f(r.w);
    *(float4*)(h + (size_t)m * ICH + i4 * 4) = r;
}

// ---------------- K3: x_proj GEMM: ssmp[m][e] += h[m][:] . xw[e][:], K-split x4 atomics
__global__ __launch_bounds__(256) void k3_xproj(
    const float* __restrict__ h,   // [M][I]
    const float* __restrict__ xw,  // [80][I]
    float* __restrict__ ssmp)      // [M][80], pre-zeroed
{
    __shared__ float4 As[64][5];   // [m][k4]
    __shared__ float4 Bs[80][5];   // [e][k4]
    const int tid = threadIdx.x;
    const int tm = tid >> 4;       // m group 0..15
    const int te = tid & 15;       // e lane 0..15
    const int m0 = blockIdx.x * 64;
    const int k_beg = blockIdx.y * 384;
    const int lrow = tid >> 2, lc4 = tid & 3;
    float4 acc[4][5] = {};
    for (int k0 = k_beg; k0 < k_beg + 384; k0 += 16) {
        As[lrow][lc4] = *(const float4*)(h + (size_t)(m0 + lrow) * ICH + k0 + lc4 * 4);
        for (int t = tid; t < 320; t += 256)
            Bs[t >> 2][t & 3] = *(const float4*)(xw + (size_t)(t >> 2) * ICH + k0 + (t & 3) * 4);
        __syncthreads();
        #pragma unroll
        for (int kk4 = 0; kk4 < 4; ++kk4) {
            float4 a[4], b[5];
            #pragma unroll
            for (int i = 0; i < 4; ++i) a[i] = As[tm + 16 * i][kk4];
            #pragma unroll
            for (int j = 0; j < 5; ++j) b[j] = Bs[te + 16 * j][kk4];
            #pragma unroll
            for (int i = 0; i < 4; ++i)
                #pragma unroll
                for (int j = 0; j < 5; ++j) {
                    acc[i][j].x += a[i].x * b[j].x; acc[i][j].y += a[i].y * b[j].y;
                    acc[i][j].z += a[i].z * b[j].z; acc[i][j].w += a[i].w * b[j].w;
                }
        }
        __syncthreads();
    }
    #pragma unroll
    for (int i = 0; i < 4; ++i) {
        int m = m0 + tm + 16 * i;
        #pragma unroll
        for (int j = 0; j < 5; ++j) {
            float v = acc[i][j].x + acc[i][j].y + acc[i][j].z + acc[i][j].w;
            atomicAdd(ssmp + (size_t)m * 80 + te + 16 * j, v);
        }
    }
}

// ---------------- K4: dt = softplus(ts @ dtw^T + b) via fp16 MFMA, K=48 padded to 64.
__global__ __launch_bounds__(256) void k4m(
    const float* __restrict__ ssmp,   // [M][80] (ts = cols 0..47)
    const float* __restrict__ dtw,    // [I][48]
    const float* __restrict__ dtb,    // [I]
    const float* __restrict__ alpha,  // [I]
    float* __restrict__ dt)           // [M][I]
{
    __shared__ __align__(16) f16 As[128 * 72];   // [row][72] (64 K + 8 pad)
    __shared__ __align__(16) f16 Bs[128 * 72];
    const int tid = threadIdx.x;
    const int lane = tid & 63, wave = tid >> 6;
    const int quad = lane >> 4, l16 = lane & 15;
    const int wm = wave & 1, wn = wave >> 1;
    const int m0 = blockIdx.x * 128, n0 = blockIdx.y * 128;
    const int srow = tid >> 1;          // 0..127
    const int shalf = tid & 1;          // 0..1 -> cols [0,24) or [24,48)

    {   // stage A (ts) and B (dtw), cvt to fp16, zero-pad cols 48..63
        const float* sa = ssmp + (size_t)(m0 + srow) * 80 + shalf * 24;
        const float* sb = dtw + (size_t)(n0 + srow) * 48 + shalf * 24;
        f16* da = &As[srow * 72 + shalf * 24];
        f16* db = &Bs[srow * 72 + shalf * 24];
        #pragma unroll
        for (int j = 0; j < 6; ++j) {
            float4 va = *(const float4*)(sa + 4 * j);
            float4 vb = *(const float4*)(sb + 4 * j);
            f16x4 oa = { (f16)va.x, (f16)va.y, (f16)va.z, (f16)va.w };
            f16x4 ob = { (f16)vb.x, (f16)vb.y, (f16)vb.z, (f16)vb.w };
            *(f16x4*)(da + 4 * j) = oa;
            *(f16x4*)(db + 4 * j) = ob;
        }
        if (shalf) {
            f16x8 z = {};
            *(f16x8*)&As[srow * 72 + 48] = z;
            *(f16x8*)&As[srow * 72 + 56] = z;
            *(f16x8*)&Bs[srow * 72 + 48] = z;
            *(f16x8*)&Bs[srow * 72 + 56] = z;
        }
    }
    __syncthreads();

    f32x4 acc[4][4] = {};
    #pragma unroll
    for (int ks = 0; ks < 2; ++ks) {
        f16x8 af[4], bf[4];
        #pragma unroll
        for (int mi = 0; mi < 4; ++mi)
            af[mi] = *(const f16x8*)&As[(wm * 64 + mi * 16 + l16) * 72 + ks * 32 + quad * 8];
        #pragma unroll
        for (int ni = 0; ni < 4; ++ni)
            bf[ni] = *(const f16x8*)&Bs[(wn * 64 + ni * 16 + l16) * 72 + ks * 32 + quad * 8];
        #pragma unroll
        for (int mi = 0; mi < 4; ++mi)
            #pragma unroll
            for (int ni = 0; ni < 4; ++ni)
                acc[mi][ni] = __builtin_amdgcn_mfma_f32_16x16x32_f16(
                    af[mi], bf[ni], acc[mi][ni], 0, 0, 0);
    }

    #pragma unroll
    for (int ni = 0; ni < 4; ++ni) {
        int e = n0 + wn * 64 + ni * 16 + l16;
        float bias = dtb[e];
        float al = alpha[e];
        #pragma unroll
        for (int mi = 0; mi < 4; ++mi) {
            #pragma unroll
            for (int r = 0; r < 4; ++r) {
                int m = m0 + wm * 64 + mi * 16 + quad * 4 + r;
                float x = acc[mi][ni][r] + bias;
                float sp = (x > 20.0f) ? x : __logf(1.0f + __expf(x));
                if ((m & (S_LEN - 1)) == S_LEN - 1) sp *= al;
                dt[(size_t)m * ICH + e] = sp;
            }
        }
    }
}

// ---------------- K5a: per-chunk summary, LDS-staged dt/h/B; coalesced float4 P/Sf.
// grid (I/64, NCH, B), block 256 = 64 chains x 4 n-lanes
__global__ __launch_bounds__(256) void k5a_chunk(
    const float* __restrict__ dt,    // [M][I]
    const float* __restrict__ h,     // [M][I]
    const float* __restrict__ ssmp,  // [M][80]: B cols 48..63
    const float* __restrict__ A_log, // [I][16]
    float* __restrict__ PArr,        // [NCH][B*I*16]
    float* __restrict__ SfArr)       // [NCH][B*I*16]
{
    __shared__ float2 dh[CHS * 64];  // [t][ii] = (dt, h)
    __shared__ float Bc[CHS][16];
    const int tid = threadIdx.x;
    const int n4 = tid & 3;
    const int il = tid >> 2;         // 0..63
    const int i0 = blockIdx.x * 64;
    const int i = i0 + il;
    const int c = blockIdx.y;
    const int b = blockIdx.z;
    const int s0 = c * CHS;
    const size_t row0 = (size_t)(b * S_LEN + s0) * ICH + i0;

    #pragma unroll
    for (int k = 0; k < (CHS * 64) / 256; ++k) {
        int idx = tid + k * 256;
        int t = idx >> 6, ii = idx & 63;
        float dv = dt[row0 + (size_t)t * ICH + ii];
        float hv = h[row0 + (size_t)t * ICH + ii];
        dh[idx] = make_float2(dv, hv);
    }
    if (tid < CHS * 4) {     // stage B rows: 32 t x 16 floats
        int t = tid >> 2, q = tid & 3;
        *(float4*)&Bc[t][q * 4] =
            *(const float4*)(ssmp + (size_t)(b * S_LEN + s0 + t) * 80 + 48 + q * 4);
    }

    const float L2E = 1.44269504088896f;
    float4 alv = *(const float4*)(A_log + i * NST + n4 * 4);
    float A[4] = { -expf(alv.x) * L2E, -expf(alv.y) * L2E,
                   -expf(alv.z) * L2E, -expf(alv.w) * L2E };
    float st[4] = {};
    float cdt = 0.f;
    __syncthreads();
    #pragma unroll 4
    for (int t = 0; t < CHS; ++t) {
        float2 dhv = dh[t * 64 + il];
        float4 Bv = *(const float4*)&Bc[t][n4 * 4];
        cdt += dhv.x;
        float x = dhv.x * dhv.y;
        #pragma unroll
        for (int j = 0; j < 4; ++j) {
            float dA = exp2f(A[j] * dhv.x);
            st[j] = fmaf(dA, st[j], x * (&Bv.x)[j]);
        }
    }
    size_t base = (size_t)c * CSTR + (size_t)(b * ICH + i) * NST + n4 * 4;
    float4 Pv = { exp2f(A[0] * cdt), exp2f(A[1] * cdt),
                  exp2f(A[2] * cdt), exp2f(A[3] * cdt) };   // telescoped prod dA
    float4 Sv = { st[0], st[1], st[2], st[3] };
    *(float4*)(PArr + base)  = Pv;
    *(float4*)(SfArr + base) = Sv;
}

// ---------------- K5b: combine chunk summaries into carry-in per chunk.
// NOTE: CIn aliases PArr — read P/Sf before writing CIn at the same index.
__global__ __launch_bounds__(256) void k5b_carry(
    const float* PArr,       // [NCH][49152]
    const float* __restrict__ SfArr,
    float* CIn)              // aliases PArr
{
    int idx = blockIdx.x * 256 + threadIdx.x;   // over B*I*16 = 49152
    float carry = 0.f;
    #pragma unroll 8
    for (int c = 0; c < NCH; ++c) {
        size_t a = (size_t)c * CSTR + idx;
        float p = PArr[a];
        float s = SfArr[a];
        CIn[a] = carry;
        carry = fmaf(p, carry, s);
    }
}

// ---------------- K5c: replay chunk with carry-in, emit y fp16; LDS-staged dt/h/g/B/C
__global__ __launch_bounds__(256) void k5c_emit(
    const float* __restrict__ dt,    // [M][I]
    const float* __restrict__ h,     // [M][I]
    const float* __restrict__ sgate, // [M][I]
    const float* __restrict__ ssmp,  // [M][80]: B 48..63, C 64..79
    const float* __restrict__ A_log, // [I][16]
    const float* __restrict__ Dp,    // [I]
    const float* __restrict__ fg,    // [I]
    const float* __restrict__ CIn,   // [NCH][49152]
    f16* __restrict__ yh)            // [M][I] fp16
{
    __shared__ float2 dh[CHS * 64];
    __shared__ float gb[CHS * 64];
    __shared__ float BC[CHS][32];    // [t][0..15]=B, [16..31]=C
    const int tid = threadIdx.x;
    const int n4 = tid & 3;
    const int il = tid >> 2;
    const int i0 = blockIdx.x * 64;
    const int i = i0 + il;
    const int c = blockIdx.y;
    const int b = blockIdx.z;
    const int s0 = c * CHS;
    const size_t row0 = (size_t)(b * S_LEN + s0) * ICH + i0;

    #pragma unroll
    for (int k = 0; k < (CHS * 64) / 256; ++k) {
        int idx = tid + k * 256;
        int t = idx >> 6, ii = idx & 63;
        float dv = dt[row0 + (size_t)t * ICH + ii];
        float hv = h[row0 + (size_t)t * ICH + ii];
        float gv = sgate[row0 + (size_t)t * ICH + ii];
        dh[idx] = make_float2(dv, hv);
        gb[idx] = gv;
    }
    {   // stage B+C rows: 32 t x 32 floats = 256 float4
        int t = tid >> 3, q = tid & 7;
        *(float4*)&BC[t][q * 4] =
            *(const float4*)(ssmp + (size_t)(b * S_LEN + s0 + t) * 80 + 48 + q * 4);
    }

    const float L2E = 1.44269504088896f;
    float4 alv = *(const float4*)(A_log + i * NST + n4 * 4);
    float A[4] = { -expf(alv.x) * L2E, -expf(alv.y) * L2E,
                   -expf(alv.z) * L2E, -expf(alv.w) * L2E };
    const float Dv = Dp[i];
    const float fgv = fg[i];
    float4 civ = *(const float4*)(CIn + (size_t)c * CSTR + (size_t)(b * ICH + i) * NST + n4 * 4);
    float st[4] = { civ.x, civ.y, civ.z, civ.w };
    f16* yout = yh + row0 + il;
    const bool last_chunk = (c == NCH - 1);
    __syncthreads();
    #pragma unroll 4
    for (int t = 0; t < CHS; ++t) {
        float2 dhv = dh[t * 64 + il];
        float4 Bv = *(const float4*)&BC[t][n4 * 4];
        float4 Cv = *(const float4*)&BC[t][16 + n4 * 4];
        float x = dhv.x * dhv.y;
        float yp = 0.f;
        #pragma unroll
        for (int j = 0; j < 4; ++j) {
            float dA = exp2f(A[j] * dhv.x);
            st[j] = fmaf(dA, st[j], x * (&Bv.x)[j]);
            yp = fmaf(st[j], (&Cv.x)[j], yp);
        }
        yp += __shfl_xor(yp, 1, 4);
        yp += __shfl_xor(yp, 2, 4);
        if (n4 == 0) {
            float yv = fmaf(dhv.y, Dv, yp) * gb[t * 64 + il];
            if (last_chunk && t == CHS - 1) yv *= fgv;
            yout[(size_t)t * ICH] = (f16)yv;
        }
    }
}

// ---------------- K6: out_proj fp16 MFMA GEMM [4096,1536] @ [768,1536]^T, async staging
__global__ __launch_bounds__(256) void k6m(
    const f16* __restrict__ Yh,    // [4096][1536]
    const f16* __restrict__ Wh,    // [768][1536]
    float* __restrict__ out)       // [M][768]
{
    __shared__ __align__(16) f16 As[128 * 32];
    __shared__ __align__(16) f16 Bs[128 * 32];
    const int tid = threadIdx.x;
    const int lane = tid & 63, wave = tid >> 6;
    const int quad = lane >> 4, l16 = lane & 15;
    const int wm = wave & 1, wn = wave >> 1;
    const int m0 = blockIdx.x * 128, n0 = blockIdx.y * 128;
    const int l_row = lane >> 2, l_c8 = (lane & 3) * 8;

    const f16* Ag = Yh + (size_t)(m0 + wave * 16 + l_row) * ICH + l_c8;
    const f16* Bg = Wh + (size_t)(n0 + wave * 16 + l_row) * ICH + l_c8;
    f16* As0 = As + (wave * 16) * 32;
    f16* As1 = As + (64 + wave * 16) * 32;
    f16* Bs0 = Bs + (wave * 16) * 32;
    f16* Bs1 = Bs + (64 + wave * 16) * 32;

    f32x4 acc[4][4] = {};
    for (int k0 = 0; k0 < ICH; k0 += 32) {
        __syncthreads();
        glds16(As0, Ag + k0);
        glds16(As1, Ag + (size_t)64 * ICH + k0);
        glds16(Bs0, Bg + k0);
        glds16(Bs1, Bg + (size_t)64 * ICH + k0);
        __syncthreads();
        f16x8 af[4], bf[4];
        #pragma unroll
        for (int mi = 0; mi < 4; ++mi)
            af[mi] = *(const f16x8*)&As[(wm * 64 + mi * 16 + l16) * 32 + quad * 8];
        #pragma unroll
        for (int ni = 0; ni < 4; ++ni)
            bf[ni] = *(const f16x8*)&Bs[(wn * 64 + ni * 16 + l16) * 32 + quad * 8];
        #pragma unroll
        for (int mi = 0; mi < 4; ++mi)
            #pragma unroll
            for (int ni = 0; ni < 4; ++ni)
                acc[mi][ni] = __builtin_amdgcn_mfma_f32_16x16x32_f16(
                    af[mi], bf[ni], acc[mi][ni], 0, 0, 0);
    }
    #pragma unroll
    for (int mi = 0; mi < 4; ++mi) {
        #pragma unroll
        for (int ni = 0; ni < 4; ++ni) {
            #pragma unroll
            for (int r = 0; r < 4; ++r) {
                int m = m0 + wm * 64 + mi * 16 + quad * 4 + r;
                int d = n0 + wn * 64 + ni * 16 + l16;
                out[(size_t)m * DMODEL + d] = acc[mi][ni][r];
            }
        }
    }
}

extern "C" void kernel_launch(void* const* d_in, const int* in_sizes, int n_in,
                              void* d_out, int out_size, void* d_ws, size_t ws_size,
                              hipStream_t stream) {
    const float* X     = (const float*)d_in[0];
    const float* W1    = (const float*)d_in[1];
    const float* CW    = (const float*)d_in[2];
    const float* CB    = (const float*)d_in[3];
    const float* XW    = (const float*)d_in[4];
    const float* DTW   = (const float*)d_in[5];
    const float* DTB   = (const float*)d_in[6];
    const float* ALOG  = (const float*)d_in[7];
    const float* DD    = (const float*)d_in[8];
    const float* OW    = (const float*)d_in[9];
    const float* ALPHA = (const float*)d_in[10];
    const float* FG    = (const float*)d_in[11];
    float* out = (float*)d_out;

    float* ws = (float*)d_ws;
    const size_t NBI = (size_t)MROWS * ICH;        // 6,291,456
    float* hidden = ws;
    float* sgate  = hidden + NBI;
    float* hbuf   = sgate + NBI;
    float* dtbuf  = hbuf + NBI;
    float* ssmp   = dtbuf + NBI;                   // 4096*80
    // halves region R1: [Xh | W1h] before k5c, reused as yh after
    f16* R1  = (f16*)(ssmp + (size_t)MROWS * 80);
    f16* Xh  = R1;                                  // 4096*768
    f16* W1h = R1 + (size_t)MROWS * DMODEL;         // 3072*768
    f16* yh  = R1;                                  // 4096*1536 (overlays Xh|W1h)
    f16* OWh = R1 + NBI;                            // 768*1536, lives until k6
    // scan summaries overlay dead hidden buffer:
    // PArr[NCH][49152] + SfArr[NCH][49152] = 6,291,456 floats = exact fit.
    float* PArr = hidden;
    float* SfA  = hidden + (size_t)NCH * CSTR;
    float* CIn  = PArr;                             // alias; k5b reads-before-writes

    const int nX = MROWS * DMODEL, nW1 = 2 * ICH * DMODEL, nOW = DMODEL * ICH;
    hipMemsetAsync(ssmp, 0, (size_t)MROWS * 80 * sizeof(float), stream);
    cvt3<<<dim3((nX + nW1 + nOW) / 1024), 256, 0, stream>>>(X, Xh, nX, W1, W1h, nW1, OW, OWh);
    k1m<<<dim3(32, 24), 256, 0, stream>>>(Xh, W1h, hidden, sgate);
    k2_conv<<<dim3((MROWS * 384) / 256), 256, 0, stream>>>(hidden, CW, CB, hbuf);
    k3_xproj<<<dim3(64, 4), 256, 0, stream>>>(hbuf, XW, ssmp);
    k4m<<<dim3(32, 12), 256, 0, stream>>>(ssmp, DTW, DTB, ALPHA, dtbuf);
    k5a_chunk<<<dim3(24, NCH, 2), 256, 0, stream>>>(dtbuf, hbuf, ssmp, ALOG, PArr, SfA);
    k5b_carry<<<dim3(192), 256, 0, stream>>>(PArr, SfA, CIn);
    k5c_emit<<<dim3(24, NCH, 2), 256, 0, stream>>>(dtbuf, hbuf, sgate, ssmp, ALOG, DD, FG, CIn, yh);
    k6m<<<dim3(32, 6), 256, 0, stream>>>(yh, OWh, out);
}

// Round 10
// 297.484 us; speedup vs baseline: 1.2968x; 1.0846x over previous
//
#include <hip/hip_runtime.h>
#include <math.h>

// AdaptedMixer — Round 10:
//  - fp16 intermediates: hidden/sgate/h stored f16 (dt stays fp32) — halves traffic
//    in k1m-write, k2, k3, k5a, k5c. Error budget ~3e-6 vs 8.39e-6 threshold.
//  - k1m/k6m: BK=64 via two stacked BK=32 LDS tile pairs (bank-optimal b128 reads
//    preserved), halving barrier/drain count in the latency-bound K-loops.
//  - ws layout (90 MB): hidden_h|sgate_h|h_h|dt|ssmp|Xh|W1h|OWh|Sf;
//    P/CIn overlay hidden_h (dead after k2), yh overlays Sf (dead after k5b).
// B=2 S=2048 Dm=768 I=1536 N=16 R=48 K=4.  M = B*S = 4096.

static constexpr int S_LEN  = 2048;
static constexpr int DMODEL = 768;
static constexpr int ICH    = 1536;
static constexpr int NST    = 16;
static constexpr int MROWS  = 4096;   // B*S
static constexpr int NCH    = 64;     // scan chunks
static constexpr int CHS    = 32;     // steps per chunk
static constexpr int CSTR   = 2 * ICH * NST;   // 49152: per-chunk summary stride

typedef _Float16 f16;
typedef f16 f16x8 __attribute__((ext_vector_type(8)));
typedef f16 f16x4 __attribute__((ext_vector_type(4)));
typedef f16 f16x2 __attribute__((ext_vector_type(2)));
typedef float f32x4 __attribute__((ext_vector_type(4)));

typedef __attribute__((address_space(3))) void lds_void;
typedef const __attribute__((address_space(1))) void glb_void;

__device__ __forceinline__ void glds16(f16* l, const f16* g) {
    __builtin_amdgcn_global_load_lds((glb_void*)g, (lds_void*)l, 16, 0, 0);
}

__device__ __forceinline__ float silu_f(float x) {
    return x / (1.0f + __expf(-x));
}

// ---------------- cvt3: three fp32->fp16 conversions in one launch
__global__ __launch_bounds__(256) void cvt3(
    const float* __restrict__ s0, f16* __restrict__ d0, int n0,
    const float* __restrict__ s1, f16* __restrict__ d1, int n1,
    const float* __restrict__ s2, f16* __restrict__ d2)
{
    int i = (blockIdx.x * 256 + threadIdx.x) * 4;
    const float* s; f16* d;
    if (i < n0)            { s = s0 + i;            d = d0 + i; }
    else if (i < n0 + n1)  { s = s1 + (i - n0);     d = d1 + (i - n0); }
    else                   { s = s2 + (i - n0 - n1); d = d2 + (i - n0 - n1); }
    float4 v = *(const float4*)s;
    f16x4 o = { (f16)v.x, (f16)v.y, (f16)v.z, (f16)v.w };
    *(f16x4*)d = o;
}

// ---------------- K1: in_proj fp16 MFMA GEMM [4096,768] @ [3072,768]^T, BK=64
__global__ __launch_bounds__(256) void k1m(
    const f16* __restrict__ Xh,    // [4096][768]
    const f16* __restrict__ Wh,    // [3072][768]
    f16* __restrict__ hidden,      // [M][I]
    f16* __restrict__ sgate)       // [M][I] (silu applied)
{
    __shared__ __align__(16) f16 As[2][128 * 32];
    __shared__ __align__(16) f16 Bs[2][128 * 32];
    const int tid = threadIdx.x;
    const int lane = tid & 63, wave = tid >> 6;
    const int quad = lane >> 4, l16 = lane & 15;
    const int wm = wave & 1, wn = wave >> 1;
    const int m0 = blockIdx.x * 128, n0 = blockIdx.y * 128;
    const int l_row = lane >> 2, l_c8 = (lane & 3) * 8;

    const f16* Ag = Xh + (size_t)(m0 + wave * 16 + l_row) * 768 + l_c8;
    const f16* Bg = Wh + (size_t)(n0 + wave * 16 + l_row) * 768 + l_c8;
    const int lo = (wave * 16) * 32, hi = (64 + wave * 16) * 32;

    f32x4 acc[4][4] = {};
    for (int k0 = 0; k0 < 768; k0 += 64) {
        __syncthreads();
        glds16(&As[0][lo], Ag + k0);
        glds16(&As[0][hi], Ag + (size_t)64 * 768 + k0);
        glds16(&Bs[0][lo], Bg + k0);
        glds16(&Bs[0][hi], Bg + (size_t)64 * 768 + k0);
        glds16(&As[1][lo], Ag + k0 + 32);
        glds16(&As[1][hi], Ag + (size_t)64 * 768 + k0 + 32);
        glds16(&Bs[1][lo], Bg + k0 + 32);
        glds16(&Bs[1][hi], Bg + (size_t)64 * 768 + k0 + 32);
        __syncthreads();
        #pragma unroll
        for (int half = 0; half < 2; ++half) {
            f16x8 af[4], bf[4];
            #pragma unroll
            for (int mi = 0; mi < 4; ++mi)
                af[mi] = *(const f16x8*)&As[half][(wm * 64 + mi * 16 + l16) * 32 + quad * 8];
            #pragma unroll
            for (int ni = 0; ni < 4; ++ni)
                bf[ni] = *(const f16x8*)&Bs[half][(wn * 64 + ni * 16 + l16) * 32 + quad * 8];
            #pragma unroll
            for (int mi = 0; mi < 4; ++mi)
                #pragma unroll
                for (int ni = 0; ni < 4; ++ni)
                    acc[mi][ni] = __builtin_amdgcn_mfma_f32_16x16x32_f16(
                        af[mi], bf[ni], acc[mi][ni], 0, 0, 0);
        }
    }
    const bool isGate = (n0 >= ICH);
    f16* outp = isGate ? sgate : hidden;
    const int e0 = (isGate ? (n0 - ICH) : n0) + wn * 64 + l16;
    #pragma unroll
    for (int mi = 0; mi < 4; ++mi) {
        #pragma unroll
        for (int ni = 0; ni < 4; ++ni) {
            #pragma unroll
            for (int r = 0; r < 4; ++r) {
                int m = m0 + wm * 64 + mi * 16 + quad * 4 + r;
                int e = e0 + ni * 16;
                float v = acc[mi][ni][r];
                if (isGate) v = silu_f(v);
                outp[(size_t)m * ICH + e] = (f16)v;
            }
        }
    }
}

// ---------------- K2: causal depthwise conv (K=4) + bias + silu, f16 in/out
__global__ __launch_bounds__(256) void k2_conv(
    const f16* __restrict__ hidden,    // [M][I]
    const float* __restrict__ conv_w,  // [I][4]
    const float* __restrict__ conv_b,  // [I]
    f16* __restrict__ h)               // [M][I]
{
    int idx = blockIdx.x * 256 + threadIdx.x;      // over M * (I/4)
    int i4 = idx % 384;
    int m  = idx / 384;
    int s  = m & (S_LEN - 1);
    const f16* base = hidden + (size_t)m * ICH + i4 * 4;
    const int c0 = i4 * 4;
    float4 wa = *(const float4*)(conv_w + (c0 + 0) * 4);
    float4 wb = *(const float4*)(conv_w + (c0 + 1) * 4);
    float4 wc = *(const float4*)(conv_w + (c0 + 2) * 4);
    float4 wd = *(const float4*)(conv_w + (c0 + 3) * 4);
    float4 bv = *(const float4*)(conv_b + c0);
    f16x4 z = {};
    f16x4 x0 = *(const f16x4*)(base);
    f16x4 x1 = (s >= 1) ? *(const f16x4*)(base - ICH)     : z;
    f16x4 x2 = (s >= 2) ? *(const f16x4*)(base - 2 * ICH) : z;
    f16x4 x3 = (s >= 3) ? *(const f16x4*)(base - 3 * ICH) : z;
    float r0 = bv.x + wa.x * (float)x3[0] + wa.y * (float)x2[0] + wa.z * (float)x1[0] + wa.w * (float)x0[0];
    float r1 = bv.y + wb.x * (float)x3[1] + wb.y * (float)x2[1] + wb.z * (float)x1[1] + wb.w * (float)x0[1];
    float r2 = bv.z + wc.x * (float)x3[2] + wc.y * (float)x2[2] + wc.z * (float)x1[2] + wc.w * (float)x0[2];
    float r3 = bv.w + wd.x * (float)x3[3] + wd.y * (float)x2[3] + wd.z * (float)x1[3] + wd.w * (float)x0[3];
    f16x4 r = { (f16)silu_f(r0), (f16)silu_f(r1), (f16)silu_f(r2), (f16)silu_f(r3) };
    *(f16x4*)(h + (size_t)m * ICH + i4 * 4) = r;
}

// ---------------- K3: x_proj GEMM: ssmp[m][e] += h[m][:] . xw[e][:], K-split x4 atomics
__global__ __launch_bounds__(256) void k3_xproj(
    const f16* __restrict__ h,     // [M][I] f16
    const float* __restrict__ xw,  // [80][I]
    float* __restrict__ ssmp)      // [M][80], pre-zeroed
{
    __shared__ float4 As[64][5];   // [m][k4]
    __shared__ float4 Bs[80][5];   // [e][k4]
    const int tid = threadIdx.x;
    const int tm = tid >> 4;       // m group 0..15
    const int te = tid & 15;       // e lane 0..15
    const int m0 = blockIdx.x * 64;
    const int k_beg = blockIdx.y * 384;
    const int lrow = tid >> 2, lc4 = tid & 3;
    float4 acc[4][5] = {};
    for (int k0 = k_beg; k0 < k_beg + 384; k0 += 16) {
        f16x4 hv = *(const f16x4*)(h + (size_t)(m0 + lrow) * ICH + k0 + lc4 * 4);
        As[lrow][lc4] = make_float4((float)hv[0], (float)hv[1], (float)hv[2], (float)hv[3]);
        for (int t = tid; t < 320; t += 256)
            Bs[t >> 2][t & 3] = *(const float4*)(xw + (size_t)(t >> 2) * ICH + k0 + (t & 3) * 4);
        __syncthreads();
        #pragma unroll
        for (int kk4 = 0; kk4 < 4; ++kk4) {
            float4 a[4], b[5];
            #pragma unroll
            for (int i = 0; i < 4; ++i) a[i] = As[tm + 16 * i][kk4];
            #pragma unroll
            for (int j = 0; j < 5; ++j) b[j] = Bs[te + 16 * j][kk4];
            #pragma unroll
            for (int i = 0; i < 4; ++i)
                #pragma unroll
                for (int j = 0; j < 5; ++j) {
                    acc[i][j].x += a[i].x * b[j].x; acc[i][j].y += a[i].y * b[j].y;
                    acc[i][j].z += a[i].z * b[j].z; acc[i][j].w += a[i].w * b[j].w;
                }
        }
        __syncthreads();
    }
    #pragma unroll
    for (int i = 0; i < 4; ++i) {
        int m = m0 + tm + 16 * i;
        #pragma unroll
        for (int j = 0; j < 5; ++j) {
            float v = acc[i][j].x + acc[i][j].y + acc[i][j].z + acc[i][j].w;
            atomicAdd(ssmp + (size_t)m * 80 + te + 16 * j, v);
        }
    }
}

// ---------------- K4: dt = softplus(ts @ dtw^T + b) via fp16 MFMA, K=48 padded to 64.
__global__ __launch_bounds__(256) void k4m(
    const float* __restrict__ ssmp,   // [M][80] (ts = cols 0..47)
    const float* __restrict__ dtw,    // [I][48]
    const float* __restrict__ dtb,    // [I]
    const float* __restrict__ alpha,  // [I]
    float* __restrict__ dt)           // [M][I]
{
    __shared__ __align__(16) f16 As[128 * 72];   // [row][72] (64 K + 8 pad)
    __shared__ __align__(16) f16 Bs[128 * 72];
    const int tid = threadIdx.x;
    const int lane = tid & 63, wave = tid >> 6;
    const int quad = lane >> 4, l16 = lane & 15;
    const int wm = wave & 1, wn = wave >> 1;
    const int m0 = blockIdx.x * 128, n0 = blockIdx.y * 128;
    const int srow = tid >> 1;          // 0..127
    const int shalf = tid & 1;          // 0..1 -> cols [0,24) or [24,48)

    {   // stage A (ts) and B (dtw), cvt to fp16, zero-pad cols 48..63
        const float* sa = ssmp + (size_t)(m0 + srow) * 80 + shalf * 24;
        const float* sb = dtw + (size_t)(n0 + srow) * 48 + shalf * 24;
        f16* da = &As[srow * 72 + shalf * 24];
        f16* db = &Bs[srow * 72 + shalf * 24];
        #pragma unroll
        for (int j = 0; j < 6; ++j) {
            float4 va = *(const float4*)(sa + 4 * j);
            float4 vb = *(const float4*)(sb + 4 * j);
            f16x4 oa = { (f16)va.x, (f16)va.y, (f16)va.z, (f16)va.w };
            f16x4 ob = { (f16)vb.x, (f16)vb.y, (f16)vb.z, (f16)vb.w };
            *(f16x4*)(da + 4 * j) = oa;
            *(f16x4*)(db + 4 * j) = ob;
        }
        if (shalf) {
            f16x8 z = {};
            *(f16x8*)&As[srow * 72 + 48] = z;
            *(f16x8*)&As[srow * 72 + 56] = z;
            *(f16x8*)&Bs[srow * 72 + 48] = z;
            *(f16x8*)&Bs[srow * 72 + 56] = z;
        }
    }
    __syncthreads();

    f32x4 acc[4][4] = {};
    #pragma unroll
    for (int ks = 0; ks < 2; ++ks) {
        f16x8 af[4], bf[4];
        #pragma unroll
        for (int mi = 0; mi < 4; ++mi)
            af[mi] = *(const f16x8*)&As[(wm * 64 + mi * 16 + l16) * 72 + ks * 32 + quad * 8];
        #pragma unroll
        for (int ni = 0; ni < 4; ++ni)
            bf[ni] = *(const f16x8*)&Bs[(wn * 64 + ni * 16 + l16) * 72 + ks * 32 + quad * 8];
        #pragma unroll
        for (int mi = 0; mi < 4; ++mi)
            #pragma unroll
            for (int ni = 0; ni < 4; ++ni)
                acc[mi][ni] = __builtin_amdgcn_mfma_f32_16x16x32_f16(
                    af[mi], bf[ni], acc[mi][ni], 0, 0, 0);
    }

    #pragma unroll
    for (int ni = 0; ni < 4; ++ni) {
        int e = n0 + wn * 64 + ni * 16 + l16;
        float bias = dtb[e];
        float al = alpha[e];
        #pragma unroll
        for (int mi = 0; mi < 4; ++mi) {
            #pragma unroll
            for (int r = 0; r < 4; ++r) {
                int m = m0 + wm * 64 + mi * 16 + quad * 4 + r;
                float x = acc[mi][ni][r] + bias;
                float sp = (x > 20.0f) ? x : __logf(1.0f + __expf(x));
                if ((m & (S_LEN - 1)) == S_LEN - 1) sp *= al;
                dt[(size_t)m * ICH + e] = sp;
            }
        }
    }
}

// ---------------- K5a: per-chunk summary, LDS-staged dt/h/B; coalesced float4 P/Sf.
// grid (I/64, NCH, B), block 256 = 64 chains x 4 n-lanes
__global__ __launch_bounds__(256) void k5a_chunk(
    const float* __restrict__ dt,    // [M][I]
    const f16* __restrict__ h,       // [M][I] f16
    const float* __restrict__ ssmp,  // [M][80]: B cols 48..63
    const float* __restrict__ A_log, // [I][16]
    float* __restrict__ PArr,        // [NCH][B*I*16]
    float* __restrict__ SfArr)       // [NCH][B*I*16]
{
    __shared__ float dts[CHS * 64];
    __shared__ float hs[CHS * 64];
    __shared__ float Bc[CHS][16];
    const int tid = threadIdx.x;
    const int n4 = tid & 3;
    const int il = tid >> 2;         // 0..63
    const int i0 = blockIdx.x * 64;
    const int i = i0 + il;
    const int c = blockIdx.y;
    const int b = blockIdx.z;
    const int s0 = c * CHS;
    const size_t row0 = (size_t)(b * S_LEN + s0) * ICH + i0;

    #pragma unroll
    for (int k = 0; k < (CHS * 64) / 256; ++k) {
        int idx = tid + k * 256;
        dts[idx] = dt[row0 + (size_t)(idx >> 6) * ICH + (idx & 63)];
    }
    #pragma unroll
    for (int k = 0; k < (CHS * 64) / 512; ++k) {
        int idx = (tid + k * 256) * 2;
        f16x2 v = *(const f16x2*)(h + row0 + (size_t)(idx >> 6) * ICH + (idx & 63));
        hs[idx] = (float)v[0]; hs[idx + 1] = (float)v[1];
    }
    if (tid < CHS * 4) {     // stage B rows: 32 t x 16 floats
        int t = tid >> 2, q = tid & 3;
        *(float4*)&Bc[t][q * 4] =
            *(const float4*)(ssmp + (size_t)(b * S_LEN + s0 + t) * 80 + 48 + q * 4);
    }

    const float L2E = 1.44269504088896f;
    float4 alv = *(const float4*)(A_log + i * NST + n4 * 4);
    float A[4] = { -expf(alv.x) * L2E, -expf(alv.y) * L2E,
                   -expf(alv.z) * L2E, -expf(alv.w) * L2E };
    float st[4] = {};
    float cdt = 0.f;
    __syncthreads();
    #pragma unroll 4
    for (int t = 0; t < CHS; ++t) {
        float dtv = dts[t * 64 + il];
        float hv  = hs[t * 64 + il];
        float4 Bv = *(const float4*)&Bc[t][n4 * 4];
        cdt += dtv;
        float x = dtv * hv;
        #pragma unroll
        for (int j = 0; j < 4; ++j) {
            float dA = exp2f(A[j] * dtv);
            st[j] = fmaf(dA, st[j], x * (&Bv.x)[j]);
        }
    }
    size_t base = (size_t)c * CSTR + (size_t)(b * ICH + i) * NST + n4 * 4;
    float4 Pv = { exp2f(A[0] * cdt), exp2f(A[1] * cdt),
                  exp2f(A[2] * cdt), exp2f(A[3] * cdt) };   // telescoped prod dA
    float4 Sv = { st[0], st[1], st[2], st[3] };
    *(float4*)(PArr + base)  = Pv;
    *(float4*)(SfArr + base) = Sv;
}

// ---------------- K5b: combine chunk summaries into carry-in per chunk.
// NOTE: CIn aliases PArr — read P/Sf before writing CIn at the same index.
__global__ __launch_bounds__(256) void k5b_carry(
    const float* PArr,       // [NCH][49152]
    const float* __restrict__ SfArr,
    float* CIn)              // aliases PArr
{
    int idx = blockIdx.x * 256 + threadIdx.x;   // over B*I*16 = 49152
    float carry = 0.f;
    #pragma unroll 8
    for (int c = 0; c < NCH; ++c) {
        size_t a = (size_t)c * CSTR + idx;
        float p = PArr[a];
        float s = SfArr[a];
        CIn[a] = carry;
        carry = fmaf(p, carry, s);
    }
}

// ---------------- K5c: replay chunk with carry-in, emit y fp16; LDS-staged inputs
__global__ __launch_bounds__(256) void k5c_emit(
    const float* __restrict__ dt,    // [M][I]
    const f16* __restrict__ h,       // [M][I] f16
    const f16* __restrict__ sgate,   // [M][I] f16
    const float* __restrict__ ssmp,  // [M][80]: B 48..63, C 64..79
    const float* __restrict__ A_log, // [I][16]
    const float* __restrict__ Dp,    // [I]
    const float* __restrict__ fg,    // [I]
    const float* __restrict__ CIn,   // [NCH][49152]
    f16* __restrict__ yh)            // [M][I] fp16
{
    __shared__ float dts[CHS * 64];
    __shared__ float hs[CHS * 64];
    __shared__ float gs[CHS * 64];
    __shared__ float BC[CHS][32];    // [t][0..15]=B, [16..31]=C
    const int tid = threadIdx.x;
    const int n4 = tid & 3;
    const int il = tid >> 2;
    const int i0 = blockIdx.x * 64;
    const int i = i0 + il;
    const int c = blockIdx.y;
    const int b = blockIdx.z;
    const int s0 = c * CHS;
    const size_t row0 = (size_t)(b * S_LEN + s0) * ICH + i0;

    #pragma unroll
    for (int k = 0; k < (CHS * 64) / 256; ++k) {
        int idx = tid + k * 256;
        dts[idx] = dt[row0 + (size_t)(idx >> 6) * ICH + (idx & 63)];
    }
    #pragma unroll
    for (int k = 0; k < (CHS * 64) / 512; ++k) {
        int idx = (tid + k * 256) * 2;
        size_t g_off = row0 + (size_t)(idx >> 6) * ICH + (idx & 63);
        f16x2 v = *(const f16x2*)(h + g_off);
        f16x2 w = *(const f16x2*)(sgate + g_off);
        hs[idx] = (float)v[0]; hs[idx + 1] = (float)v[1];
        gs[idx] = (float)w[0]; gs[idx + 1] = (float)w[1];
    }
    {   // stage B+C rows: 32 t x 32 floats = 256 float4
        int t = tid >> 3, q = tid & 7;
        *(float4*)&BC[t][q * 4] =
            *(const float4*)(ssmp + (size_t)(b * S_LEN + s0 + t) * 80 + 48 + q * 4);
    }

    const float L2E = 1.44269504088896f;
    float4 alv = *(const float4*)(A_log + i * NST + n4 * 4);
    float A[4] = { -expf(alv.x) * L2E, -expf(alv.y) * L2E,
                   -expf(alv.z) * L2E, -expf(alv.w) * L2E };
    const float Dv = Dp[i];
    const float fgv = fg[i];
    float4 civ = *(const float4*)(CIn + (size_t)c * CSTR + (size_t)(b * ICH + i) * NST + n4 * 4);
    float st[4] = { civ.x, civ.y, civ.z, civ.w };
    f16* yout = yh + row0 + il;
    const bool last_chunk = (c == NCH - 1);
    __syncthreads();
    #pragma unroll 4
    for (int t = 0; t < CHS; ++t) {
        float dtv = dts[t * 64 + il];
        float hv  = hs[t * 64 + il];
        float4 Bv = *(const float4*)&BC[t][n4 * 4];
        float4 Cv = *(const float4*)&BC[t][16 + n4 * 4];
        float x = dtv * hv;
        float yp = 0.f;
        #pragma unroll
        for (int j = 0; j < 4; ++j) {
            float dA = exp2f(A[j] * dtv);
            st[j] = fmaf(dA, st[j], x * (&Bv.x)[j]);
            yp = fmaf(st[j], (&Cv.x)[j], yp);
        }
        yp += __shfl_xor(yp, 1, 4);
        yp += __shfl_xor(yp, 2, 4);
        if (n4 == 0) {
            float yv = fmaf(hv, Dv, yp) * gs[t * 64 + il];
            if (last_chunk && t == CHS - 1) yv *= fgv;
            yout[(size_t)t * ICH] = (f16)yv;
        }
    }
}

// ---------------- K6: out_proj fp16 MFMA GEMM [4096,1536] @ [768,1536]^T, BK=64
__global__ __launch_bounds__(256) void k6m(
    const f16* __restrict__ Yh,    // [4096][1536]
    const f16* __restrict__ Wh,    // [768][1536]
    float* __restrict__ out)       // [M][768]
{
    __shared__ __align__(16) f16 As[2][128 * 32];
    __shared__ __align__(16) f16 Bs[2][128 * 32];
    const int tid = threadIdx.x;
    const int lane = tid & 63, wave = tid >> 6;
    const int quad = lane >> 4, l16 = lane & 15;
    const int wm = wave & 1, wn = wave >> 1;
    const int m0 = blockIdx.x * 128, n0 = blockIdx.y * 128;
    const int l_row = lane >> 2, l_c8 = (lane & 3) * 8;

    const f16* Ag = Yh + (size_t)(m0 + wave * 16 + l_row) * ICH + l_c8;
    const f16* Bg = Wh + (size_t)(n0 + wave * 16 + l_row) * ICH + l_c8;
    const int lo = (wave * 16) * 32, hi = (64 + wave * 16) * 32;

    f32x4 acc[4][4] = {};
    for (int k0 = 0; k0 < ICH; k0 += 64) {
        __syncthreads();
        glds16(&As[0][lo], Ag + k0);
        glds16(&As[0][hi], Ag + (size_t)64 * ICH + k0);
        glds16(&Bs[0][lo], Bg + k0);
        glds16(&Bs[0][hi], Bg + (size_t)64 * ICH + k0);
        glds16(&As[1][lo], Ag + k0 + 32);
        glds16(&As[1][hi], Ag + (size_t)64 * ICH + k0 + 32);
        glds16(&Bs[1][lo], Bg + k0 + 32);
        glds16(&Bs[1][hi], Bg + (size_t)64 * ICH + k0 + 32);
        __syncthreads();
        #pragma unroll
        for (int half = 0; half < 2; ++half) {
            f16x8 af[4], bf[4];
            #pragma unroll
            for (int mi = 0; mi < 4; ++mi)
                af[mi] = *(const f16x8*)&As[half][(wm * 64 + mi * 16 + l16) * 32 + quad * 8];
            #pragma unroll
            for (int ni = 0; ni < 4; ++ni)
                bf[ni] = *(const f16x8*)&Bs[half][(wn * 64 + ni * 16 + l16) * 32 + quad * 8];
            #pragma unroll
            for (int mi = 0; mi < 4; ++mi)
                #pragma unroll
                for (int ni = 0; ni < 4; ++ni)
                    acc[mi][ni] = __builtin_amdgcn_mfma_f32_16x16x32_f16(
                        af[mi], bf[ni], acc[mi][ni], 0, 0, 0);
        }
    }
    #pragma unroll
    for (int mi = 0; mi < 4; ++mi) {
        #pragma unroll
        for (int ni = 0; ni < 4; ++ni) {
            #pragma unroll
            for (int r = 0; r < 4; ++r) {
                int m = m0 + wm * 64 + mi * 16 + quad * 4 + r;
                int d = n0 + wn * 64 + ni * 16 + l16;
                out[(size_t)m * DMODEL + d] = acc[mi][ni][r];
            }
        }
    }
}

extern "C" void kernel_launch(void* const* d_in, const int* in_sizes, int n_in,
                              void* d_out, int out_size, void* d_ws, size_t ws_size,
                              hipStream_t stream) {
    const float* X     = (const float*)d_in[0];
    const float* W1    = (const float*)d_in[1];
    const float* CW    = (const float*)d_in[2];
    const float* CB    = (const float*)d_in[3];
    const float* XW    = (const float*)d_in[4];
    const float* DTW   = (const float*)d_in[5];
    const float* DTB   = (const float*)d_in[6];
    const float* ALOG  = (const float*)d_in[7];
    const float* DD    = (const float*)d_in[8];
    const float* OW    = (const float*)d_in[9];
    const float* ALPHA = (const float*)d_in[10];
    const float* FG    = (const float*)d_in[11];
    float* out = (float*)d_out;

    const size_t NBI = (size_t)MROWS * ICH;         // 6,291,456
    f16* hidden_h = (f16*)d_ws;                     // 12.58 MB
    f16* sgate_h  = hidden_h + NBI;
    f16* h_h      = sgate_h + NBI;
    float* dtbuf  = (float*)(h_h + NBI);            // 25.17 MB
    float* ssmp   = dtbuf + NBI;                    // 1.31 MB
    f16* Xh       = (f16*)(ssmp + (size_t)MROWS * 80);
    f16* W1h      = Xh + (size_t)MROWS * DMODEL;
    f16* OWh      = W1h + (size_t)2 * ICH * DMODEL;
    float* SfA    = (float*)(OWh + (size_t)DMODEL * ICH);   // 12.58 MB
    // overlays: P/CIn on hidden_h (dead after k2); yh on Sf (dead after k5b)
    float* PArr = (float*)hidden_h;                 // NCH*CSTR floats = 12.58 MB exact
    float* CIn  = PArr;
    f16* yh     = (f16*)SfA;                        // NBI f16 = 12.58 MB exact

    const int nX = MROWS * DMODEL, nW1 = 2 * ICH * DMODEL, nOW = DMODEL * ICH;
    hipMemsetAsync(ssmp, 0, (size_t)MROWS * 80 * sizeof(float), stream);
    cvt3<<<dim3((nX + nW1 + nOW) / 1024), 256, 0, stream>>>(X, Xh, nX, W1, W1h, nW1, OW, OWh);
    k1m<<<dim3(32, 24), 256, 0, stream>>>(Xh, W1h, hidden_h, sgate_h);
    k2_conv<<<dim3((MROWS * 384) / 256), 256, 0, stream>>>(hidden_h, CW, CB, h_h);
    k3_xproj<<<dim3(64, 4), 256, 0, stream>>>(h_h, XW, ssmp);
    k4m<<<dim3(32, 12), 256, 0, stream>>>(ssmp, DTW, DTB, ALPHA, dtbuf);
    k5a_chunk<<<dim3(24, NCH, 2), 256, 0, stream>>>(dtbuf, h_h, ssmp, ALOG, PArr, SfA);
    k5b_carry<<<dim3(192), 256, 0, stream>>>(PArr, SfA, CIn);
    k5c_emit<<<dim3(24, NCH, 2), 256, 0, stream>>>(dtbuf, h_h, sgate_h, ssmp, ALOG, DD, FG, CIn, yh);
    k6m<<<dim3(32, 6), 256, 0, stream>>>(yh, OWh, out);
}

// Round 11
// 279.686 us; speedup vs baseline: 1.3793x; 1.0636x over previous
//
#include <hip/hip_runtime.h>
#include <math.h>

// AdaptedMixer — Round 11:
//  - dt stored f16 (k4m out, k5a/k5c stage): -25 MB traffic, fewer staging instrs.
//  - k3 -> fp16 MFMA (128x80 tile, ksplit x8, async A-stage, fp32 atomic epilogue).
// B=2 S=2048 Dm=768 I=1536 N=16 R=48 K=4.  M = B*S = 4096.

static constexpr int S_LEN  = 2048;
static constexpr int DMODEL = 768;
static constexpr int ICH    = 1536;
static constexpr int NST    = 16;
static constexpr int MROWS  = 4096;   // B*S
static constexpr int NCH    = 64;     // scan chunks
static constexpr int CHS    = 32;     // steps per chunk
static constexpr int CSTR   = 2 * ICH * NST;   // 49152: per-chunk summary stride

typedef _Float16 f16;
typedef f16 f16x8 __attribute__((ext_vector_type(8)));
typedef f16 f16x4 __attribute__((ext_vector_type(4)));
typedef f16 f16x2 __attribute__((ext_vector_type(2)));
typedef float f32x4 __attribute__((ext_vector_type(4)));

typedef __attribute__((address_space(3))) void lds_void;
typedef const __attribute__((address_space(1))) void glb_void;

__device__ __forceinline__ void glds16(f16* l, const f16* g) {
    __builtin_amdgcn_global_load_lds((glb_void*)g, (lds_void*)l, 16, 0, 0);
}

__device__ __forceinline__ float silu_f(float x) {
    return x / (1.0f + __expf(-x));
}

// ---------------- cvt3: three fp32->fp16 conversions in one launch
__global__ __launch_bounds__(256) void cvt3(
    const float* __restrict__ s0, f16* __restrict__ d0, int n0,
    const float* __restrict__ s1, f16* __restrict__ d1, int n1,
    const float* __restrict__ s2, f16* __restrict__ d2)
{
    int i = (blockIdx.x * 256 + threadIdx.x) * 4;
    const float* s; f16* d;
    if (i < n0)            { s = s0 + i;            d = d0 + i; }
    else if (i < n0 + n1)  { s = s1 + (i - n0);     d = d1 + (i - n0); }
    else                   { s = s2 + (i - n0 - n1); d = d2 + (i - n0 - n1); }
    float4 v = *(const float4*)s;
    f16x4 o = { (f16)v.x, (f16)v.y, (f16)v.z, (f16)v.w };
    *(f16x4*)d = o;
}

// ---------------- K1: in_proj fp16 MFMA GEMM [4096,768] @ [3072,768]^T, BK=64
__global__ __launch_bounds__(256) void k1m(
    const f16* __restrict__ Xh,    // [4096][768]
    const f16* __restrict__ Wh,    // [3072][768]
    f16* __restrict__ hidden,      // [M][I]
    f16* __restrict__ sgate)       // [M][I] (silu applied)
{
    __shared__ __align__(16) f16 As[2][128 * 32];
    __shared__ __align__(16) f16 Bs[2][128 * 32];
    const int tid = threadIdx.x;
    const int lane = tid & 63, wave = tid >> 6;
    const int quad = lane >> 4, l16 = lane & 15;
    const int wm = wave & 1, wn = wave >> 1;
    const int m0 = blockIdx.x * 128, n0 = blockIdx.y * 128;
    const int l_row = lane >> 2, l_c8 = (lane & 3) * 8;

    const f16* Ag = Xh + (size_t)(m0 + wave * 16 + l_row) * 768 + l_c8;
    const f16* Bg = Wh + (size_t)(n0 + wave * 16 + l_row) * 768 + l_c8;
    const int lo = (wave * 16) * 32, hi = (64 + wave * 16) * 32;

    f32x4 acc[4][4] = {};
    for (int k0 = 0; k0 < 768; k0 += 64) {
        __syncthreads();
        glds16(&As[0][lo], Ag + k0);
        glds16(&As[0][hi], Ag + (size_t)64 * 768 + k0);
        glds16(&Bs[0][lo], Bg + k0);
        glds16(&Bs[0][hi], Bg + (size_t)64 * 768 + k0);
        glds16(&As[1][lo], Ag + k0 + 32);
        glds16(&As[1][hi], Ag + (size_t)64 * 768 + k0 + 32);
        glds16(&Bs[1][lo], Bg + k0 + 32);
        glds16(&Bs[1][hi], Bg + (size_t)64 * 768 + k0 + 32);
        __syncthreads();
        #pragma unroll
        for (int half = 0; half < 2; ++half) {
            f16x8 af[4], bf[4];
            #pragma unroll
            for (int mi = 0; mi < 4; ++mi)
                af[mi] = *(const f16x8*)&As[half][(wm * 64 + mi * 16 + l16) * 32 + quad * 8];
            #pragma unroll
            for (int ni = 0; ni < 4; ++ni)
                bf[ni] = *(const f16x8*)&Bs[half][(wn * 64 + ni * 16 + l16) * 32 + quad * 8];
            #pragma unroll
            for (int mi = 0; mi < 4; ++mi)
                #pragma unroll
                for (int ni = 0; ni < 4; ++ni)
                    acc[mi][ni] = __builtin_amdgcn_mfma_f32_16x16x32_f16(
                        af[mi], bf[ni], acc[mi][ni], 0, 0, 0);
        }
    }
    const bool isGate = (n0 >= ICH);
    f16* outp = isGate ? sgate : hidden;
    const int e0 = (isGate ? (n0 - ICH) : n0) + wn * 64 + l16;
    #pragma unroll
    for (int mi = 0; mi < 4; ++mi) {
        #pragma unroll
        for (int ni = 0; ni < 4; ++ni) {
            #pragma unroll
            for (int r = 0; r < 4; ++r) {
                int m = m0 + wm * 64 + mi * 16 + quad * 4 + r;
                int e = e0 + ni * 16;
                float v = acc[mi][ni][r];
                if (isGate) v = silu_f(v);
                outp[(size_t)m * ICH + e] = (f16)v;
            }
        }
    }
}

// ---------------- K2: causal depthwise conv (K=4) + bias + silu, f16 in/out
__global__ __launch_bounds__(256) void k2_conv(
    const f16* __restrict__ hidden,    // [M][I]
    const float* __restrict__ conv_w,  // [I][4]
    const float* __restrict__ conv_b,  // [I]
    f16* __restrict__ h)               // [M][I]
{
    int idx = blockIdx.x * 256 + threadIdx.x;      // over M * (I/4)
    int i4 = idx % 384;
    int m  = idx / 384;
    int s  = m & (S_LEN - 1);
    const f16* base = hidden + (size_t)m * ICH + i4 * 4;
    const int c0 = i4 * 4;
    float4 wa = *(const float4*)(conv_w + (c0 + 0) * 4);
    float4 wb = *(const float4*)(conv_w + (c0 + 1) * 4);
    float4 wc = *(const float4*)(conv_w + (c0 + 2) * 4);
    float4 wd = *(const float4*)(conv_w + (c0 + 3) * 4);
    float4 bv = *(const float4*)(conv_b + c0);
    f16x4 z = {};
    f16x4 x0 = *(const f16x4*)(base);
    f16x4 x1 = (s >= 1) ? *(const f16x4*)(base - ICH)     : z;
    f16x4 x2 = (s >= 2) ? *(const f16x4*)(base - 2 * ICH) : z;
    f16x4 x3 = (s >= 3) ? *(const f16x4*)(base - 3 * ICH) : z;
    float r0 = bv.x + wa.x * (float)x3[0] + wa.y * (float)x2[0] + wa.z * (float)x1[0] + wa.w * (float)x0[0];
    float r1 = bv.y + wb.x * (float)x3[1] + wb.y * (float)x2[1] + wb.z * (float)x1[1] + wb.w * (float)x0[1];
    float r2 = bv.z + wc.x * (float)x3[2] + wc.y * (float)x2[2] + wc.z * (float)x1[2] + wc.w * (float)x0[2];
    float r3 = bv.w + wd.x * (float)x3[3] + wd.y * (float)x2[3] + wd.z * (float)x1[3] + wd.w * (float)x0[3];
    f16x4 r = { (f16)silu_f(r0), (f16)silu_f(r1), (f16)silu_f(r2), (f16)silu_f(r3) };
    *(f16x4*)(h + (size_t)m * ICH + i4 * 4) = r;
}

// ---------------- K3: x_proj fp16 MFMA GEMM -> ssmp[m][e] (+=, atomics), ksplit x8
// tile 128m x 80e; 4 waves each cover 32 m-rows x 80 cols; BK=32, K=192 per block.
__global__ __launch_bounds__(256) void k3m(
    const f16* __restrict__ h,     // [M][I] f16
    const float* __restrict__ xw,  // [80][I] fp32
    float* __restrict__ ssmp)      // [M][80], pre-zeroed
{
    __shared__ __align__(16) f16 Ah[128 * 32];
    __shared__ __align__(16) f16 Bh[80 * 32];
    const int tid = threadIdx.x;
    const int lane = tid & 63, wave = tid >> 6;
    const int quad = lane >> 4, l16 = lane & 15;
    const int m0 = blockIdx.x * 128;
    const int kbeg = blockIdx.y * 192;
    const int l_row = lane >> 2, l_c8 = (lane & 3) * 8;

    const f16* Ag = h + (size_t)(m0 + wave * 32 + l_row) * ICH + l_c8;
    f16* As0 = Ah + (wave * 32) * 32;
    f16* As1 = Ah + (wave * 32 + 16) * 32;

    f32x4 acc[2][5] = {};
    for (int k0 = kbeg; k0 < kbeg + 192; k0 += 32) {
        __syncthreads();
        glds16(As0, Ag + k0);
        glds16(As1, Ag + (size_t)16 * ICH + k0);
        {   // stage B: 80 rows x 32 cols fp32 -> f16
            int c4 = (tid & 7) * 4;
            for (int r = tid >> 3; r < 80; r += 32) {
                float4 v = *(const float4*)(xw + (size_t)r * ICH + k0 + c4);
                f16x4 o = { (f16)v.x, (f16)v.y, (f16)v.z, (f16)v.w };
                *(f16x4*)&Bh[r * 32 + c4] = o;
            }
        }
        __syncthreads();
        f16x8 af[2], bf[5];
        #pragma unroll
        for (int mi = 0; mi < 2; ++mi)
            af[mi] = *(const f16x8*)&Ah[(wave * 32 + mi * 16 + l16) * 32 + quad * 8];
        #pragma unroll
        for (int j = 0; j < 5; ++j)
            bf[j] = *(const f16x8*)&Bh[(j * 16 + l16) * 32 + quad * 8];
        #pragma unroll
        for (int mi = 0; mi < 2; ++mi)
            #pragma unroll
            for (int j = 0; j < 5; ++j)
                acc[mi][j] = __builtin_amdgcn_mfma_f32_16x16x32_f16(
                    af[mi], bf[j], acc[mi][j], 0, 0, 0);
    }
    #pragma unroll
    for (int mi = 0; mi < 2; ++mi) {
        #pragma unroll
        for (int j = 0; j < 5; ++j) {
            #pragma unroll
            for (int r = 0; r < 4; ++r) {
                int m = m0 + wave * 32 + mi * 16 + quad * 4 + r;
                atomicAdd(ssmp + (size_t)m * 80 + j * 16 + l16, acc[mi][j][r]);
            }
        }
    }
}

// ---------------- K4: dt = softplus(ts @ dtw^T + b) via fp16 MFMA, K=48 padded to 64.
__global__ __launch_bounds__(256) void k4m(
    const float* __restrict__ ssmp,   // [M][80] (ts = cols 0..47)
    const float* __restrict__ dtw,    // [I][48]
    const float* __restrict__ dtb,    // [I]
    const float* __restrict__ alpha,  // [I]
    f16* __restrict__ dt)             // [M][I] f16
{
    __shared__ __align__(16) f16 As[128 * 72];   // [row][72] (64 K + 8 pad)
    __shared__ __align__(16) f16 Bs[128 * 72];
    const int tid = threadIdx.x;
    const int lane = tid & 63, wave = tid >> 6;
    const int quad = lane >> 4, l16 = lane & 15;
    const int wm = wave & 1, wn = wave >> 1;
    const int m0 = blockIdx.x * 128, n0 = blockIdx.y * 128;
    const int srow = tid >> 1;          // 0..127
    const int shalf = tid & 1;          // 0..1 -> cols [0,24) or [24,48)

    {   // stage A (ts) and B (dtw), cvt to fp16, zero-pad cols 48..63
        const float* sa = ssmp + (size_t)(m0 + srow) * 80 + shalf * 24;
        const float* sb = dtw + (size_t)(n0 + srow) * 48 + shalf * 24;
        f16* da = &As[srow * 72 + shalf * 24];
        f16* db = &Bs[srow * 72 + shalf * 24];
        #pragma unroll
        for (int j = 0; j < 6; ++j) {
            float4 va = *(const float4*)(sa + 4 * j);
            float4 vb = *(const float4*)(sb + 4 * j);
            f16x4 oa = { (f16)va.x, (f16)va.y, (f16)va.z, (f16)va.w };
            f16x4 ob = { (f16)vb.x, (f16)vb.y, (f16)vb.z, (f16)vb.w };
            *(f16x4*)(da + 4 * j) = oa;
            *(f16x4*)(db + 4 * j) = ob;
        }
        if (shalf) {
            f16x8 z = {};
            *(f16x8*)&As[srow * 72 + 48] = z;
            *(f16x8*)&As[srow * 72 + 56] = z;
            *(f16x8*)&Bs[srow * 72 + 48] = z;
            *(f16x8*)&Bs[srow * 72 + 56] = z;
        }
    }
    __syncthreads();

    f32x4 acc[4][4] = {};
    #pragma unroll
    for (int ks = 0; ks < 2; ++ks) {
        f16x8 af[4], bf[4];
        #pragma unroll
        for (int mi = 0; mi < 4; ++mi)
            af[mi] = *(const f16x8*)&As[(wm * 64 + mi * 16 + l16) * 72 + ks * 32 + quad * 8];
        #pragma unroll
        for (int ni = 0; ni < 4; ++ni)
            bf[ni] = *(const f16x8*)&Bs[(wn * 64 + ni * 16 + l16) * 72 + ks * 32 + quad * 8];
        #pragma unroll
        for (int mi = 0; mi < 4; ++mi)
            #pragma unroll
            for (int ni = 0; ni < 4; ++ni)
                acc[mi][ni] = __builtin_amdgcn_mfma_f32_16x16x32_f16(
                    af[mi], bf[ni], acc[mi][ni], 0, 0, 0);
    }

    #pragma unroll
    for (int ni = 0; ni < 4; ++ni) {
        int e = n0 + wn * 64 + ni * 16 + l16;
        float bias = dtb[e];
        float al = alpha[e];
        #pragma unroll
        for (int mi = 0; mi < 4; ++mi) {
            #pragma unroll
            for (int r = 0; r < 4; ++r) {
                int m = m0 + wm * 64 + mi * 16 + quad * 4 + r;
                float x = acc[mi][ni][r] + bias;
                float sp = (x > 20.0f) ? x : __logf(1.0f + __expf(x));
                if ((m & (S_LEN - 1)) == S_LEN - 1) sp *= al;
                dt[(size_t)m * ICH + e] = (f16)sp;
            }
        }
    }
}

// ---------------- K5a: per-chunk summary, LDS-staged dt/h/B; coalesced float4 P/Sf.
__global__ __launch_bounds__(256) void k5a_chunk(
    const f16* __restrict__ dt,      // [M][I] f16
    const f16* __restrict__ h,       // [M][I] f16
    const float* __restrict__ ssmp,  // [M][80]: B cols 48..63
    const float* __restrict__ A_log, // [I][16]
    float* __restrict__ PArr,        // [NCH][B*I*16]
    float* __restrict__ SfArr)       // [NCH][B*I*16]
{
    __shared__ float dts[CHS * 64];
    __shared__ float hs[CHS * 64];
    __shared__ float Bc[CHS][16];
    const int tid = threadIdx.x;
    const int n4 = tid & 3;
    const int il = tid >> 2;         // 0..63
    const int i0 = blockIdx.x * 64;
    const int i = i0 + il;
    const int c = blockIdx.y;
    const int b = blockIdx.z;
    const int s0 = c * CHS;
    const size_t row0 = (size_t)(b * S_LEN + s0) * ICH + i0;

    #pragma unroll
    for (int k = 0; k < (CHS * 64) / 512; ++k) {
        int idx = (tid + k * 256) * 2;
        size_t g_off = row0 + (size_t)(idx >> 6) * ICH + (idx & 63);
        f16x2 dv = *(const f16x2*)(dt + g_off);
        f16x2 hv = *(const f16x2*)(h + g_off);
        dts[idx] = (float)dv[0]; dts[idx + 1] = (float)dv[1];
        hs[idx]  = (float)hv[0]; hs[idx + 1]  = (float)hv[1];
    }
    if (tid < CHS * 4) {     // stage B rows: 32 t x 16 floats
        int t = tid >> 2, q = tid & 3;
        *(float4*)&Bc[t][q * 4] =
            *(const float4*)(ssmp + (size_t)(b * S_LEN + s0 + t) * 80 + 48 + q * 4);
    }

    const float L2E = 1.44269504088896f;
    float4 alv = *(const float4*)(A_log + i * NST + n4 * 4);
    float A[4] = { -expf(alv.x) * L2E, -expf(alv.y) * L2E,
                   -expf(alv.z) * L2E, -expf(alv.w) * L2E };
    float st[4] = {};
    float cdt = 0.f;
    __syncthreads();
    #pragma unroll 4
    for (int t = 0; t < CHS; ++t) {
        float dtv = dts[t * 64 + il];
        float hv  = hs[t * 64 + il];
        float4 Bv = *(const float4*)&Bc[t][n4 * 4];
        cdt += dtv;
        float x = dtv * hv;
        #pragma unroll
        for (int j = 0; j < 4; ++j) {
            float dA = exp2f(A[j] * dtv);
            st[j] = fmaf(dA, st[j], x * (&Bv.x)[j]);
        }
    }
    size_t base = (size_t)c * CSTR + (size_t)(b * ICH + i) * NST + n4 * 4;
    float4 Pv = { exp2f(A[0] * cdt), exp2f(A[1] * cdt),
                  exp2f(A[2] * cdt), exp2f(A[3] * cdt) };   // telescoped prod dA
    float4 Sv = { st[0], st[1], st[2], st[3] };
    *(float4*)(PArr + base)  = Pv;
    *(float4*)(SfArr + base) = Sv;
}

// ---------------- K5b: combine chunk summaries into carry-in per chunk.
// NOTE: CIn aliases PArr — read P/Sf before writing CIn at the same index.
__global__ __launch_bounds__(256) void k5b_carry(
    const float* PArr,       // [NCH][49152]
    const float* __restrict__ SfArr,
    float* CIn)              // aliases PArr
{
    int idx = blockIdx.x * 256 + threadIdx.x;   // over B*I*16 = 49152
    float carry = 0.f;
    #pragma unroll 8
    for (int c = 0; c < NCH; ++c) {
        size_t a = (size_t)c * CSTR + idx;
        float p = PArr[a];
        float s = SfArr[a];
        CIn[a] = carry;
        carry = fmaf(p, carry, s);
    }
}

// ---------------- K5c: replay chunk with carry-in, emit y fp16; LDS-staged inputs
__global__ __launch_bounds__(256) void k5c_emit(
    const f16* __restrict__ dt,      // [M][I] f16
    const f16* __restrict__ h,       // [M][I] f16
    const f16* __restrict__ sgate,   // [M][I] f16
    const float* __restrict__ ssmp,  // [M][80]: B 48..63, C 64..79
    const float* __restrict__ A_log, // [I][16]
    const float* __restrict__ Dp,    // [I]
    const float* __restrict__ fg,    // [I]
    const float* __restrict__ CIn,   // [NCH][49152]
    f16* __restrict__ yh)            // [M][I] fp16
{
    __shared__ float dts[CHS * 64];
    __shared__ float hs[CHS * 64];
    __shared__ float gs[CHS * 64];
    __shared__ float BC[CHS][32];    // [t][0..15]=B, [16..31]=C
    const int tid = threadIdx.x;
    const int n4 = tid & 3;
    const int il = tid >> 2;
    const int i0 = blockIdx.x * 64;
    const int i = i0 + il;
    const int c = blockIdx.y;
    const int b = blockIdx.z;
    const int s0 = c * CHS;
    const size_t row0 = (size_t)(b * S_LEN + s0) * ICH + i0;

    #pragma unroll
    for (int k = 0; k < (CHS * 64) / 512; ++k) {
        int idx = (tid + k * 256) * 2;
        size_t g_off = row0 + (size_t)(idx >> 6) * ICH + (idx & 63);
        f16x2 dv = *(const f16x2*)(dt + g_off);
        f16x2 v = *(const f16x2*)(h + g_off);
        f16x2 w = *(const f16x2*)(sgate + g_off);
        dts[idx] = (float)dv[0]; dts[idx + 1] = (float)dv[1];
        hs[idx] = (float)v[0]; hs[idx + 1] = (float)v[1];
        gs[idx] = (float)w[0]; gs[idx + 1] = (float)w[1];
    }
    {   // stage B+C rows: 32 t x 32 floats = 256 float4
        int t = tid >> 3, q = tid & 7;
        *(float4*)&BC[t][q * 4] =
            *(const float4*)(ssmp + (size_t)(b * S_LEN + s0 + t) * 80 + 48 + q * 4);
    }

    const float L2E = 1.44269504088896f;
    float4 alv = *(const float4*)(A_log + i * NST + n4 * 4);
    float A[4] = { -expf(alv.x) * L2E, -expf(alv.y) * L2E,
                   -expf(alv.z) * L2E, -expf(alv.w) * L2E };
    const float Dv = Dp[i];
    const float fgv = fg[i];
    float4 civ = *(const float4*)(CIn + (size_t)c * CSTR + (size_t)(b * ICH + i) * NST + n4 * 4);
    float st[4] = { civ.x, civ.y, civ.z, civ.w };
    f16* yout = yh + row0 + il;
    const bool last_chunk = (c == NCH - 1);
    __syncthreads();
    #pragma unroll 4
    for (int t = 0; t < CHS; ++t) {
        float dtv = dts[t * 64 + il];
        float hv  = hs[t * 64 + il];
        float4 Bv = *(const float4*)&BC[t][n4 * 4];
        float4 Cv = *(const float4*)&BC[t][16 + n4 * 4];
        float x = dtv * hv;
        float yp = 0.f;
        #pragma unroll
        for (int j = 0; j < 4; ++j) {
            float dA = exp2f(A[j] * dtv);
            st[j] = fmaf(dA, st[j], x * (&Bv.x)[j]);
            yp = fmaf(st[j], (&Cv.x)[j], yp);
        }
        yp += __shfl_xor(yp, 1, 4);
        yp += __shfl_xor(yp, 2, 4);
        if (n4 == 0) {
            float yv = fmaf(hv, Dv, yp) * gs[t * 64 + il];
            if (last_chunk && t == CHS - 1) yv *= fgv;
            yout[(size_t)t * ICH] = (f16)yv;
        }
    }
}

// ---------------- K6: out_proj fp16 MFMA GEMM [4096,1536] @ [768,1536]^T, BK=64
__global__ __launch_bounds__(256) void k6m(
    const f16* __restrict__ Yh,    // [4096][1536]
    const f16* __restrict__ Wh,    // [768][1536]
    float* __restrict__ out)       // [M][768]
{
    __shared__ __align__(16) f16 As[2][128 * 32];
    __shared__ __align__(16) f16 Bs[2][128 * 32];
    const int tid = threadIdx.x;
    const int lane = tid & 63, wave = tid >> 6;
    const int quad = lane >> 4, l16 = lane & 15;
    const int wm = wave & 1, wn = wave >> 1;
    const int m0 = blockIdx.x * 128, n0 = blockIdx.y * 128;
    const int l_row = lane >> 2, l_c8 = (lane & 3) * 8;

    const f16* Ag = Yh + (size_t)(m0 + wave * 16 + l_row) * ICH + l_c8;
    const f16* Bg = Wh + (size_t)(n0 + wave * 16 + l_row) * ICH + l_c8;
    const int lo = (wave * 16) * 32, hi = (64 + wave * 16) * 32;

    f32x4 acc[4][4] = {};
    for (int k0 = 0; k0 < ICH; k0 += 64) {
        __syncthreads();
        glds16(&As[0][lo], Ag + k0);
        glds16(&As[0][hi], Ag + (size_t)64 * ICH + k0);
        glds16(&Bs[0][lo], Bg + k0);
        glds16(&Bs[0][hi], Bg + (size_t)64 * ICH + k0);
        glds16(&As[1][lo], Ag + k0 + 32);
        glds16(&As[1][hi], Ag + (size_t)64 * ICH + k0 + 32);
        glds16(&Bs[1][lo], Bg + k0 + 32);
        glds16(&Bs[1][hi], Bg + (size_t)64 * ICH + k0 + 32);
        __syncthreads();
        #pragma unroll
        for (int half = 0; half < 2; ++half) {
            f16x8 af[4], bf[4];
            #pragma unroll
            for (int mi = 0; mi < 4; ++mi)
                af[mi] = *(const f16x8*)&As[half][(wm * 64 + mi * 16 + l16) * 32 + quad * 8];
            #pragma unroll
            for (int ni = 0; ni < 4; ++ni)
                bf[ni] = *(const f16x8*)&Bs[half][(wn * 64 + ni * 16 + l16) * 32 + quad * 8];
            #pragma unroll
            for (int mi = 0; mi < 4; ++mi)
                #pragma unroll
                for (int ni = 0; ni < 4; ++ni)
                    acc[mi][ni] = __builtin_amdgcn_mfma_f32_16x16x32_f16(
                        af[mi], bf[ni], acc[mi][ni], 0, 0, 0);
        }
    }
    #pragma unroll
    for (int mi = 0; mi < 4; ++mi) {
        #pragma unroll
        for (int ni = 0; ni < 4; ++ni) {
            #pragma unroll
            for (int r = 0; r < 4; ++r) {
                int m = m0 + wm * 64 + mi * 16 + quad * 4 + r;
                int d = n0 + wn * 64 + ni * 16 + l16;
                out[(size_t)m * DMODEL + d] = acc[mi][ni][r];
            }
        }
    }
}

extern "C" void kernel_launch(void* const* d_in, const int* in_sizes, int n_in,
                              void* d_out, int out_size, void* d_ws, size_t ws_size,
                              hipStream_t stream) {
    const float* X     = (const float*)d_in[0];
    const float* W1    = (const float*)d_in[1];
    const float* CW    = (const float*)d_in[2];
    const float* CB    = (const float*)d_in[3];
    const float* XW    = (const float*)d_in[4];
    const float* DTW   = (const float*)d_in[5];
    const float* DTB   = (const float*)d_in[6];
    const float* ALOG  = (const float*)d_in[7];
    const float* DD    = (const float*)d_in[8];
    const float* OW    = (const float*)d_in[9];
    const float* ALPHA = (const float*)d_in[10];
    const float* FG    = (const float*)d_in[11];
    float* out = (float*)d_out;

    const size_t NBI = (size_t)MROWS * ICH;         // 6,291,456
    f16* hidden_h = (f16*)d_ws;                     // 12.58 MB
    f16* sgate_h  = hidden_h + NBI;
    f16* h_h      = sgate_h + NBI;
    f16* dt_h     = h_h + NBI;                      // f16 now
    float* ssmp   = (float*)(dt_h + NBI);           // 1.31 MB
    f16* Xh       = (f16*)(ssmp + (size_t)MROWS * 80);
    f16* W1h      = Xh + (size_t)MROWS * DMODEL;
    f16* OWh      = W1h + (size_t)2 * ICH * DMODEL;
    float* SfA    = (float*)(OWh + (size_t)DMODEL * ICH);   // 12.58 MB
    // overlays: P/CIn on hidden_h (dead after k2); yh on Sf (dead after k5b)
    float* PArr = (float*)hidden_h;                 // NCH*CSTR floats = 12.58 MB exact
    float* CIn  = PArr;
    f16* yh     = (f16*)SfA;                        // NBI f16 = 12.58 MB exact

    const int nX = MROWS * DMODEL, nW1 = 2 * ICH * DMODEL, nOW = DMODEL * ICH;
    hipMemsetAsync(ssmp, 0, (size_t)MROWS * 80 * sizeof(float), stream);
    cvt3<<<dim3((nX + nW1 + nOW) / 1024), 256, 0, stream>>>(X, Xh, nX, W1, W1h, nW1, OW, OWh);
    k1m<<<dim3(32, 24), 256, 0, stream>>>(Xh, W1h, hidden_h, sgate_h);
    k2_conv<<<dim3((MROWS * 384) / 256), 256, 0, stream>>>(hidden_h, CW, CB, h_h);
    k3m<<<dim3(32, 8), 256, 0, stream>>>(h_h, XW, ssmp);
    k4m<<<dim3(32, 12), 256, 0, stream>>>(ssmp, DTW, DTB, ALPHA, dt_h);
    k5a_chunk<<<dim3(24, NCH, 2), 256, 0, stream>>>(dt_h, h_h, ssmp, ALOG, PArr, SfA);
    k5b_carry<<<dim3(192), 256, 0, stream>>>(PArr, SfA, CIn);
    k5c_emit<<<dim3(24, NCH, 2), 256, 0, stream>>>(dt_h, h_h, sgate_h, ssmp, ALOG, DD, FG, CIn, yh);
    k6m<<<dim3(32, 6), 256, 0, stream>>>(yh, OWh, out);
}

// Round 12
// 250.269 us; speedup vs baseline: 1.5415x; 1.1175x over previous
//
#include <hip/hip_runtime.h>
#include <math.h>

// AdaptedMixer — Round 12:
//  - k5a/k5c: raw v_exp_f32 via __builtin_amdgcn_exp2f (libm exp2f guard seq is ~5 ops).
//  - k5b: batch all 64 P/Sf loads into registers before the serial carry chain
//    (loads are independent; kills 64x HBM-latency serialization at 0.75 blk/CU).
//  - k6m: retile 128x64 (grid 32x12=384 blocks, 1.5/CU vs 0.75) .
// B=2 S=2048 Dm=768 I=1536 N=16 R=48 K=4.  M = B*S = 4096.

static constexpr int S_LEN  = 2048;
static constexpr int DMODEL = 768;
static constexpr int ICH    = 1536;
static constexpr int NST    = 16;
static constexpr int MROWS  = 4096;   // B*S
static constexpr int NCH    = 64;     // scan chunks
static constexpr int CHS    = 32;     // steps per chunk
static constexpr int CSTR   = 2 * ICH * NST;   // 49152: per-chunk summary stride

typedef _Float16 f16;
typedef f16 f16x8 __attribute__((ext_vector_type(8)));
typedef f16 f16x4 __attribute__((ext_vector_type(4)));
typedef f16 f16x2 __attribute__((ext_vector_type(2)));
typedef float f32x4 __attribute__((ext_vector_type(4)));

#if __has_builtin(__builtin_amdgcn_exp2f)
#define EXP2F(x) __builtin_amdgcn_exp2f(x)
#else
#define EXP2F(x) exp2f(x)
#endif

typedef __attribute__((address_space(3))) void lds_void;
typedef const __attribute__((address_space(1))) void glb_void;

__device__ __forceinline__ void glds16(f16* l, const f16* g) {
    __builtin_amdgcn_global_load_lds((glb_void*)g, (lds_void*)l, 16, 0, 0);
}

__device__ __forceinline__ float silu_f(float x) {
    return x / (1.0f + __expf(-x));
}

// ---------------- cvt3: three fp32->fp16 conversions in one launch
__global__ __launch_bounds__(256) void cvt3(
    const float* __restrict__ s0, f16* __restrict__ d0, int n0,
    const float* __restrict__ s1, f16* __restrict__ d1, int n1,
    const float* __restrict__ s2, f16* __restrict__ d2)
{
    int i = (blockIdx.x * 256 + threadIdx.x) * 4;
    const float* s; f16* d;
    if (i < n0)            { s = s0 + i;            d = d0 + i; }
    else if (i < n0 + n1)  { s = s1 + (i - n0);     d = d1 + (i - n0); }
    else                   { s = s2 + (i - n0 - n1); d = d2 + (i - n0 - n1); }
    float4 v = *(const float4*)s;
    f16x4 o = { (f16)v.x, (f16)v.y, (f16)v.z, (f16)v.w };
    *(f16x4*)d = o;
}

// ---------------- K1: in_proj fp16 MFMA GEMM [4096,768] @ [3072,768]^T, BK=64
__global__ __launch_bounds__(256) void k1m(
    const f16* __restrict__ Xh,    // [4096][768]
    const f16* __restrict__ Wh,    // [3072][768]
    f16* __restrict__ hidden,      // [M][I]
    f16* __restrict__ sgate)       // [M][I] (silu applied)
{
    __shared__ __align__(16) f16 As[2][128 * 32];
    __shared__ __align__(16) f16 Bs[2][128 * 32];
    const int tid = threadIdx.x;
    const int lane = tid & 63, wave = tid >> 6;
    const int quad = lane >> 4, l16 = lane & 15;
    const int wm = wave & 1, wn = wave >> 1;
    const int m0 = blockIdx.x * 128, n0 = blockIdx.y * 128;
    const int l_row = lane >> 2, l_c8 = (lane & 3) * 8;

    const f16* Ag = Xh + (size_t)(m0 + wave * 16 + l_row) * 768 + l_c8;
    const f16* Bg = Wh + (size_t)(n0 + wave * 16 + l_row) * 768 + l_c8;
    const int lo = (wave * 16) * 32, hi = (64 + wave * 16) * 32;

    f32x4 acc[4][4] = {};
    for (int k0 = 0; k0 < 768; k0 += 64) {
        __syncthreads();
        glds16(&As[0][lo], Ag + k0);
        glds16(&As[0][hi], Ag + (size_t)64 * 768 + k0);
        glds16(&Bs[0][lo], Bg + k0);
        glds16(&Bs[0][hi], Bg + (size_t)64 * 768 + k0);
        glds16(&As[1][lo], Ag + k0 + 32);
        glds16(&As[1][hi], Ag + (size_t)64 * 768 + k0 + 32);
        glds16(&Bs[1][lo], Bg + k0 + 32);
        glds16(&Bs[1][hi], Bg + (size_t)64 * 768 + k0 + 32);
        __syncthreads();
        #pragma unroll
        for (int half = 0; half < 2; ++half) {
            f16x8 af[4], bf[4];
            #pragma unroll
            for (int mi = 0; mi < 4; ++mi)
                af[mi] = *(const f16x8*)&As[half][(wm * 64 + mi * 16 + l16) * 32 + quad * 8];
            #pragma unroll
            for (int ni = 0; ni < 4; ++ni)
                bf[ni] = *(const f16x8*)&Bs[half][(wn * 64 + ni * 16 + l16) * 32 + quad * 8];
            #pragma unroll
            for (int mi = 0; mi < 4; ++mi)
                #pragma unroll
                for (int ni = 0; ni < 4; ++ni)
                    acc[mi][ni] = __builtin_amdgcn_mfma_f32_16x16x32_f16(
                        af[mi], bf[ni], acc[mi][ni], 0, 0, 0);
        }
    }
    const bool isGate = (n0 >= ICH);
    f16* outp = isGate ? sgate : hidden;
    const int e0 = (isGate ? (n0 - ICH) : n0) + wn * 64 + l16;
    #pragma unroll
    for (int mi = 0; mi < 4; ++mi) {
        #pragma unroll
        for (int ni = 0; ni < 4; ++ni) {
            #pragma unroll
            for (int r = 0; r < 4; ++r) {
                int m = m0 + wm * 64 + mi * 16 + quad * 4 + r;
                int e = e0 + ni * 16;
                float v = acc[mi][ni][r];
                if (isGate) v = silu_f(v);
                outp[(size_t)m * ICH + e] = (f16)v;
            }
        }
    }
}

// ---------------- K2: causal depthwise conv (K=4) + bias + silu, f16 in/out
__global__ __launch_bounds__(256) void k2_conv(
    const f16* __restrict__ hidden,    // [M][I]
    const float* __restrict__ conv_w,  // [I][4]
    const float* __restrict__ conv_b,  // [I]
    f16* __restrict__ h)               // [M][I]
{
    int idx = blockIdx.x * 256 + threadIdx.x;      // over M * (I/4)
    int i4 = idx % 384;
    int m  = idx / 384;
    int s  = m & (S_LEN - 1);
    const f16* base = hidden + (size_t)m * ICH + i4 * 4;
    const int c0 = i4 * 4;
    float4 wa = *(const float4*)(conv_w + (c0 + 0) * 4);
    float4 wb = *(const float4*)(conv_w + (c0 + 1) * 4);
    float4 wc = *(const float4*)(conv_w + (c0 + 2) * 4);
    float4 wd = *(const float4*)(conv_w + (c0 + 3) * 4);
    float4 bv = *(const float4*)(conv_b + c0);
    f16x4 z = {};
    f16x4 x0 = *(const f16x4*)(base);
    f16x4 x1 = (s >= 1) ? *(const f16x4*)(base - ICH)     : z;
    f16x4 x2 = (s >= 2) ? *(const f16x4*)(base - 2 * ICH) : z;
    f16x4 x3 = (s >= 3) ? *(const f16x4*)(base - 3 * ICH) : z;
    float r0 = bv.x + wa.x * (float)x3[0] + wa.y * (float)x2[0] + wa.z * (float)x1[0] + wa.w * (float)x0[0];
    float r1 = bv.y + wb.x * (float)x3[1] + wb.y * (float)x2[1] + wb.z * (float)x1[1] + wb.w * (float)x0[1];
    float r2 = bv.z + wc.x * (float)x3[2] + wc.y * (float)x2[2] + wc.z * (float)x1[2] + wc.w * (float)x0[2];
    float r3 = bv.w + wd.x * (float)x3[3] + wd.y * (float)x2[3] + wd.z * (float)x1[3] + wd.w * (float)x0[3];
    f16x4 r = { (f16)silu_f(r0), (f16)silu_f(r1), (f16)silu_f(r2), (f16)silu_f(r3) };
    *(f16x4*)(h + (size_t)m * ICH + i4 * 4) = r;
}

// ---------------- K3: x_proj fp16 MFMA GEMM -> ssmp[m][e] (+=, atomics), ksplit x8
__global__ __launch_bounds__(256) void k3m(
    const f16* __restrict__ h,     // [M][I] f16
    const float* __restrict__ xw,  // [80][I] fp32
    float* __restrict__ ssmp)      // [M][80], pre-zeroed
{
    __shared__ __align__(16) f16 Ah[128 * 32];
    __shared__ __align__(16) f16 Bh[80 * 32];
    const int tid = threadIdx.x;
    const int lane = tid & 63, wave = tid >> 6;
    const int quad = lane >> 4, l16 = lane & 15;
    const int m0 = blockIdx.x * 128;
    const int kbeg = blockIdx.y * 192;
    const int l_row = lane >> 2, l_c8 = (lane & 3) * 8;

    const f16* Ag = h + (size_t)(m0 + wave * 32 + l_row) * ICH + l_c8;
    f16* As0 = Ah + (wave * 32) * 32;
    f16* As1 = Ah + (wave * 32 + 16) * 32;

    f32x4 acc[2][5] = {};
    for (int k0 = kbeg; k0 < kbeg + 192; k0 += 32) {
        __syncthreads();
        glds16(As0, Ag + k0);
        glds16(As1, Ag + (size_t)16 * ICH + k0);
        {   // stage B: 80 rows x 32 cols fp32 -> f16
            int c4 = (tid & 7) * 4;
            for (int r = tid >> 3; r < 80; r += 32) {
                float4 v = *(const float4*)(xw + (size_t)r * ICH + k0 + c4);
                f16x4 o = { (f16)v.x, (f16)v.y, (f16)v.z, (f16)v.w };
                *(f16x4*)&Bh[r * 32 + c4] = o;
            }
        }
        __syncthreads();
        f16x8 af[2], bf[5];
        #pragma unroll
        for (int mi = 0; mi < 2; ++mi)
            af[mi] = *(const f16x8*)&Ah[(wave * 32 + mi * 16 + l16) * 32 + quad * 8];
        #pragma unroll
        for (int j = 0; j < 5; ++j)
            bf[j] = *(const f16x8*)&Bh[(j * 16 + l16) * 32 + quad * 8];
        #pragma unroll
        for (int mi = 0; mi < 2; ++mi)
            #pragma unroll
            for (int j = 0; j < 5; ++j)
                acc[mi][j] = __builtin_amdgcn_mfma_f32_16x16x32_f16(
                    af[mi], bf[j], acc[mi][j], 0, 0, 0);
    }
    #pragma unroll
    for (int mi = 0; mi < 2; ++mi) {
        #pragma unroll
        for (int j = 0; j < 5; ++j) {
            #pragma unroll
            for (int r = 0; r < 4; ++r) {
                int m = m0 + wave * 32 + mi * 16 + quad * 4 + r;
                atomicAdd(ssmp + (size_t)m * 80 + j * 16 + l16, acc[mi][j][r]);
            }
        }
    }
}

// ---------------- K4: dt = softplus(ts @ dtw^T + b) via fp16 MFMA, K=48 padded to 64.
__global__ __launch_bounds__(256) void k4m(
    const float* __restrict__ ssmp,   // [M][80] (ts = cols 0..47)
    const float* __restrict__ dtw,    // [I][48]
    const float* __restrict__ dtb,    // [I]
    const float* __restrict__ alpha,  // [I]
    f16* __restrict__ dt)             // [M][I] f16
{
    __shared__ __align__(16) f16 As[128 * 72];   // [row][72] (64 K + 8 pad)
    __shared__ __align__(16) f16 Bs[128 * 72];
    const int tid = threadIdx.x;
    const int lane = tid & 63, wave = tid >> 6;
    const int quad = lane >> 4, l16 = lane & 15;
    const int wm = wave & 1, wn = wave >> 1;
    const int m0 = blockIdx.x * 128, n0 = blockIdx.y * 128;
    const int srow = tid >> 1;          // 0..127
    const int shalf = tid & 1;          // 0..1 -> cols [0,24) or [24,48)

    {   // stage A (ts) and B (dtw), cvt to fp16, zero-pad cols 48..63
        const float* sa = ssmp + (size_t)(m0 + srow) * 80 + shalf * 24;
        const float* sb = dtw + (size_t)(n0 + srow) * 48 + shalf * 24;
        f16* da = &As[srow * 72 + shalf * 24];
        f16* db = &Bs[srow * 72 + shalf * 24];
        #pragma unroll
        for (int j = 0; j < 6; ++j) {
            float4 va = *(const float4*)(sa + 4 * j);
            float4 vb = *(const float4*)(sb + 4 * j);
            f16x4 oa = { (f16)va.x, (f16)va.y, (f16)va.z, (f16)va.w };
            f16x4 ob = { (f16)vb.x, (f16)vb.y, (f16)vb.z, (f16)vb.w };
            *(f16x4*)(da + 4 * j) = oa;
            *(f16x4*)(db + 4 * j) = ob;
        }
        if (shalf) {
            f16x8 z = {};
            *(f16x8*)&As[srow * 72 + 48] = z;
            *(f16x8*)&As[srow * 72 + 56] = z;
            *(f16x8*)&Bs[srow * 72 + 48] = z;
            *(f16x8*)&Bs[srow * 72 + 56] = z;
        }
    }
    __syncthreads();

    f32x4 acc[4][4] = {};
    #pragma unroll
    for (int ks = 0; ks < 2; ++ks) {
        f16x8 af[4], bf[4];
        #pragma unroll
        for (int mi = 0; mi < 4; ++mi)
            af[mi] = *(const f16x8*)&As[(wm * 64 + mi * 16 + l16) * 72 + ks * 32 + quad * 8];
        #pragma unroll
        for (int ni = 0; ni < 4; ++ni)
            bf[ni] = *(const f16x8*)&Bs[(wn * 64 + ni * 16 + l16) * 72 + ks * 32 + quad * 8];
        #pragma unroll
        for (int mi = 0; mi < 4; ++mi)
            #pragma unroll
            for (int ni = 0; ni < 4; ++ni)
                acc[mi][ni] = __builtin_amdgcn_mfma_f32_16x16x32_f16(
                    af[mi], bf[ni], acc[mi][ni], 0, 0, 0);
    }

    #pragma unroll
    for (int ni = 0; ni < 4; ++ni) {
        int e = n0 + wn * 64 + ni * 16 + l16;
        float bias = dtb[e];
        float al = alpha[e];
        #pragma unroll
        for (int mi = 0; mi < 4; ++mi) {
            #pragma unroll
            for (int r = 0; r < 4; ++r) {
                int m = m0 + wm * 64 + mi * 16 + quad * 4 + r;
                float x = acc[mi][ni][r] + bias;
                float sp = (x > 20.0f) ? x : __logf(1.0f + __expf(x));
                if ((m & (S_LEN - 1)) == S_LEN - 1) sp *= al;
                dt[(size_t)m * ICH + e] = (f16)sp;
            }
        }
    }
}

// ---------------- K5a: per-chunk summary, LDS-staged dt/h/B; coalesced float4 P/Sf.
__global__ __launch_bounds__(256) void k5a_chunk(
    const f16* __restrict__ dt,      // [M][I] f16
    const f16* __restrict__ h,       // [M][I] f16
    const float* __restrict__ ssmp,  // [M][80]: B cols 48..63
    const float* __restrict__ A_log, // [I][16]
    float* __restrict__ PArr,        // [NCH][B*I*16]
    float* __restrict__ SfArr)       // [NCH][B*I*16]
{
    __shared__ float dts[CHS * 64];
    __shared__ float hs[CHS * 64];
    __shared__ float Bc[CHS][16];
    const int tid = threadIdx.x;
    const int n4 = tid & 3;
    const int il = tid >> 2;         // 0..63
    const int i0 = blockIdx.x * 64;
    const int i = i0 + il;
    const int c = blockIdx.y;
    const int b = blockIdx.z;
    const int s0 = c * CHS;
    const size_t row0 = (size_t)(b * S_LEN + s0) * ICH + i0;

    #pragma unroll
    for (int k = 0; k < (CHS * 64) / 512; ++k) {
        int idx = (tid + k * 256) * 2;
        size_t g_off = row0 + (size_t)(idx >> 6) * ICH + (idx & 63);
        f16x2 dv = *(const f16x2*)(dt + g_off);
        f16x2 hv = *(const f16x2*)(h + g_off);
        dts[idx] = (float)dv[0]; dts[idx + 1] = (float)dv[1];
        hs[idx]  = (float)hv[0]; hs[idx + 1]  = (float)hv[1];
    }
    if (tid < CHS * 4) {     // stage B rows: 32 t x 16 floats
        int t = tid >> 2, q = tid & 3;
        *(float4*)&Bc[t][q * 4] =
            *(const float4*)(ssmp + (size_t)(b * S_LEN + s0 + t) * 80 + 48 + q * 4);
    }

    const float L2E = 1.44269504088896f;
    float4 alv = *(const float4*)(A_log + i * NST + n4 * 4);
    float A[4] = { -__expf(alv.x) * L2E, -__expf(alv.y) * L2E,
                   -__expf(alv.z) * L2E, -__expf(alv.w) * L2E };
    float st[4] = {};
    float cdt = 0.f;
    __syncthreads();
    #pragma unroll 4
    for (int t = 0; t < CHS; ++t) {
        float dtv = dts[t * 64 + il];
        float hv  = hs[t * 64 + il];
        float4 Bv = *(const float4*)&Bc[t][n4 * 4];
        cdt += dtv;
        float x = dtv * hv;
        #pragma unroll
        for (int j = 0; j < 4; ++j) {
            float dA = EXP2F(A[j] * dtv);
            st[j] = fmaf(dA, st[j], x * (&Bv.x)[j]);
        }
    }
    size_t base = (size_t)c * CSTR + (size_t)(b * ICH + i) * NST + n4 * 4;
    float4 Pv = { EXP2F(A[0] * cdt), EXP2F(A[1] * cdt),
                  EXP2F(A[2] * cdt), EXP2F(A[3] * cdt) };   // telescoped prod dA
    float4 Sv = { st[0], st[1], st[2], st[3] };
    *(float4*)(PArr + base)  = Pv;
    *(float4*)(SfArr + base) = Sv;
}

// ---------------- K5b: combine chunk summaries into carry-in per chunk.
// Loads are independent of the carry chain: batch all 128 loads first (MLP),
// then run the serial scan from registers. CIn aliases PArr (reads done first).
__global__ __launch_bounds__(256) void k5b_carry(
    const float* PArr,       // [NCH][49152]
    const float* __restrict__ SfArr,
    float* CIn)              // aliases PArr
{
    int idx = blockIdx.x * 256 + threadIdx.x;   // over B*I*16 = 49152
    float p[NCH], s[NCH];
    #pragma unroll
    for (int c = 0; c < NCH; ++c) {
        size_t a = (size_t)c * CSTR + idx;
        p[c] = PArr[a];
        s[c] = SfArr[a];
    }
    float carry = 0.f;
    #pragma unroll
    for (int c = 0; c < NCH; ++c) {
        CIn[(size_t)c * CSTR + idx] = carry;
        carry = fmaf(p[c], carry, s[c]);
    }
}

// ---------------- K5c: replay chunk with carry-in, emit y fp16; LDS-staged inputs
__global__ __launch_bounds__(256) void k5c_emit(
    const f16* __restrict__ dt,      // [M][I] f16
    const f16* __restrict__ h,       // [M][I] f16
    const f16* __restrict__ sgate,   // [M][I] f16
    const float* __restrict__ ssmp,  // [M][80]: B 48..63, C 64..79
    const float* __restrict__ A_log, // [I][16]
    const float* __restrict__ Dp,    // [I]
    const float* __restrict__ fg,    // [I]
    const float* __restrict__ CIn,   // [NCH][49152]
    f16* __restrict__ yh)            // [M][I] fp16
{
    __shared__ float dts[CHS * 64];
    __shared__ float hs[CHS * 64];
    __shared__ float gs[CHS * 64];
    __shared__ float BC[CHS][32];    // [t][0..15]=B, [16..31]=C
    const int tid = threadIdx.x;
    const int n4 = tid & 3;
    const int il = tid >> 2;
    const int i0 = blockIdx.x * 64;
    const int i = i0 + il;
    const int c = blockIdx.y;
    const int b = blockIdx.z;
    const int s0 = c * CHS;
    const size_t row0 = (size_t)(b * S_LEN + s0) * ICH + i0;

    #pragma unroll
    for (int k = 0; k < (CHS * 64) / 512; ++k) {
        int idx = (tid + k * 256) * 2;
        size_t g_off = row0 + (size_t)(idx >> 6) * ICH + (idx & 63);
        f16x2 dv = *(const f16x2*)(dt + g_off);
        f16x2 v = *(const f16x2*)(h + g_off);
        f16x2 w = *(const f16x2*)(sgate + g_off);
        dts[idx] = (float)dv[0]; dts[idx + 1] = (float)dv[1];
        hs[idx] = (float)v[0]; hs[idx + 1] = (float)v[1];
        gs[idx] = (float)w[0]; gs[idx + 1] = (float)w[1];
    }
    {   // stage B+C rows: 32 t x 32 floats = 256 float4
        int t = tid >> 3, q = tid & 7;
        *(float4*)&BC[t][q * 4] =
            *(const float4*)(ssmp + (size_t)(b * S_LEN + s0 + t) * 80 + 48 + q * 4);
    }

    const float L2E = 1.44269504088896f;
    float4 alv = *(const float4*)(A_log + i * NST + n4 * 4);
    float A[4] = { -__expf(alv.x) * L2E, -__expf(alv.y) * L2E,
                   -__expf(alv.z) * L2E, -__expf(alv.w) * L2E };
    const float Dv = Dp[i];
    const float fgv = fg[i];
    float4 civ = *(const float4*)(CIn + (size_t)c * CSTR + (size_t)(b * ICH + i) * NST + n4 * 4);
    float st[4] = { civ.x, civ.y, civ.z, civ.w };
    f16* yout = yh + row0 + il;
    const bool last_chunk = (c == NCH - 1);
    __syncthreads();
    #pragma unroll 4
    for (int t = 0; t < CHS; ++t) {
        float dtv = dts[t * 64 + il];
        float hv  = hs[t * 64 + il];
        float4 Bv = *(const float4*)&BC[t][n4 * 4];
        float4 Cv = *(const float4*)&BC[t][16 + n4 * 4];
        float x = dtv * hv;
        float yp = 0.f;
        #pragma unroll
        for (int j = 0; j < 4; ++j) {
            float dA = EXP2F(A[j] * dtv);
            st[j] = fmaf(dA, st[j], x * (&Bv.x)[j]);
            yp = fmaf(st[j], (&Cv.x)[j], yp);
        }
        yp += __shfl_xor(yp, 1, 4);
        yp += __shfl_xor(yp, 2, 4);
        if (n4 == 0) {
            float yv = fmaf(hv, Dv, yp) * gs[t * 64 + il];
            if (last_chunk && t == CHS - 1) yv *= fgv;
            yout[(size_t)t * ICH] = (f16)yv;
        }
    }
}

// ---------------- K6: out_proj fp16 MFMA GEMM [4096,1536] @ [768,1536]^T
// tile 128m x 64n (grid 32x12 = 384 blocks), BK=64; waves 2x2, each 64m x 32n.
__global__ __launch_bounds__(256) void k6m(
    const f16* __restrict__ Yh,    // [4096][1536]
    const f16* __restrict__ Wh,    // [768][1536]
    float* __restrict__ out)       // [M][768]
{
    __shared__ __align__(16) f16 As[2][128 * 32];
    __shared__ __align__(16) f16 Bs[2][64 * 32];
    const int tid = threadIdx.x;
    const int lane = tid & 63, wave = tid >> 6;
    const int quad = lane >> 4, l16 = lane & 15;
    const int wm = wave & 1, wn = wave >> 1;   // wn in 0..1
    const int m0 = blockIdx.x * 128, n0 = blockIdx.y * 64;
    const int l_row = lane >> 2, l_c8 = (lane & 3) * 8;

    const f16* Ag = Yh + (size_t)(m0 + wave * 16 + l_row) * ICH + l_c8;
    const f16* Bg = Wh + (size_t)(n0 + wave * 16 + l_row) * ICH + l_c8;
    const int aLo = (wave * 16) * 32, aHi = (64 + wave * 16) * 32;
    const int bOff = (wave * 16) * 32;

    f32x4 acc[4][2] = {};
    for (int k0 = 0; k0 < ICH; k0 += 64) {
        __syncthreads();
        glds16(&As[0][aLo], Ag + k0);
        glds16(&As[0][aHi], Ag + (size_t)64 * ICH + k0);
        glds16(&Bs[0][bOff], Bg + k0);
        glds16(&As[1][aLo], Ag + k0 + 32);
        glds16(&As[1][aHi], Ag + (size_t)64 * ICH + k0 + 32);
        glds16(&Bs[1][bOff], Bg + k0 + 32);
        __syncthreads();
        #pragma unroll
        for (int half = 0; half < 2; ++half) {
            f16x8 af[4], bf[2];
            #pragma unroll
            for (int mi = 0; mi < 4; ++mi)
                af[mi] = *(const f16x8*)&As[half][(wm * 64 + mi * 16 + l16) * 32 + quad * 8];
            #pragma unroll
            for (int ni = 0; ni < 2; ++ni)
                bf[ni] = *(const f16x8*)&Bs[half][(wn * 32 + ni * 16 + l16) * 32 + quad * 8];
            #pragma unroll
            for (int mi = 0; mi < 4; ++mi)
                #pragma unroll
                for (int ni = 0; ni < 2; ++ni)
                    acc[mi][ni] = __builtin_amdgcn_mfma_f32_16x16x32_f16(
                        af[mi], bf[ni], acc[mi][ni], 0, 0, 0);
        }
    }
    #pragma unroll
    for (int mi = 0; mi < 4; ++mi) {
        #pragma unroll
        for (int ni = 0; ni < 2; ++ni) {
            #pragma unroll
            for (int r = 0; r < 4; ++r) {
                int m = m0 + wm * 64 + mi * 16 + quad * 4 + r;
                int d = n0 + wn * 32 + ni * 16 + l16;
                out[(size_t)m * DMODEL + d] = acc[mi][ni][r];
            }
        }
    }
}

extern "C" void kernel_launch(void* const* d_in, const int* in_sizes, int n_in,
                              void* d_out, int out_size, void* d_ws, size_t ws_size,
                              hipStream_t stream) {
    const float* X     = (const float*)d_in[0];
    const float* W1    = (const float*)d_in[1];
    const float* CW    = (const float*)d_in[2];
    const float* CB    = (const float*)d_in[3];
    const float* XW    = (const float*)d_in[4];
    const float* DTW   = (const float*)d_in[5];
    const float* DTB   = (const float*)d_in[6];
    const float* ALOG  = (const float*)d_in[7];
    const float* DD    = (const float*)d_in[8];
    const float* OW    = (const float*)d_in[9];
    const float* ALPHA = (const float*)d_in[10];
    const float* FG    = (const float*)d_in[11];
    float* out = (float*)d_out;

    const size_t NBI = (size_t)MROWS * ICH;         // 6,291,456
    f16* hidden_h = (f16*)d_ws;                     // 12.58 MB
    f16* sgate_h  = hidden_h + NBI;
    f16* h_h      = sgate_h + NBI;
    f16* dt_h     = h_h + NBI;                      // f16
    float* ssmp   = (float*)(dt_h + NBI);           // 1.31 MB
    f16* Xh       = (f16*)(ssmp + (size_t)MROWS * 80);
    f16* W1h      = Xh + (size_t)MROWS * DMODEL;
    f16* OWh      = W1h + (size_t)2 * ICH * DMODEL;
    float* SfA    = (float*)(OWh + (size_t)DMODEL * ICH);   // 12.58 MB
    // overlays: P/CIn on hidden_h (dead after k2); yh on Sf (dead after k5b)
    float* PArr = (float*)hidden_h;                 // NCH*CSTR floats = 12.58 MB exact
    float* CIn  = PArr;
    f16* yh     = (f16*)SfA;                        // NBI f16 = 12.58 MB exact

    const int nX = MROWS * DMODEL, nW1 = 2 * ICH * DMODEL, nOW = DMODEL * ICH;
    hipMemsetAsync(ssmp, 0, (size_t)MROWS * 80 * sizeof(float), stream);
    cvt3<<<dim3((nX + nW1 + nOW) / 1024), 256, 0, stream>>>(X, Xh, nX, W1, W1h, nW1, OW, OWh);
    k1m<<<dim3(32, 24), 256, 0, stream>>>(Xh, W1h, hidden_h, sgate_h);
    k2_conv<<<dim3((MROWS * 384) / 256), 256, 0, stream>>>(hidden_h, CW, CB, h_h);
    k3m<<<dim3(32, 8), 256, 0, stream>>>(h_h, XW, ssmp);
    k4m<<<dim3(32, 12), 256, 0, stream>>>(ssmp, DTW, DTB, ALPHA, dt_h);
    k5a_chunk<<<dim3(24, NCH, 2), 256, 0, stream>>>(dt_h, h_h, ssmp, ALOG, PArr, SfA);
    k5b_carry<<<dim3(192), 256, 0, stream>>>(PArr, SfA, CIn);
    k5c_emit<<<dim3(24, NCH, 2), 256, 0, stream>>>(dt_h, h_h, sgate_h, ssmp, ALOG, DD, FG, CIn, yh);
    k6m<<<dim3(32, 12), 256, 0, stream>>>(yh, OWh, out);
}

// Round 13
// 246.710 us; speedup vs baseline: 1.5637x; 1.0144x over previous
//
#include <hip/hip_runtime.h>
#include <math.h>

// AdaptedMixer — Round 13:
//  - k1m retiled 128x64 (grid 32x48 = 1536 blocks, 6/CU; LDS 24 KB) — same
//    latency-hiding fix that worked for k6m/scan: more resident blocks cover
//    the per-iteration vmcnt(0)+barrier drains.
//  - k3m ksplit x16 (96 K per block, 512 blocks).
// B=2 S=2048 Dm=768 I=1536 N=16 R=48 K=4.  M = B*S = 4096.

static constexpr int S_LEN  = 2048;
static constexpr int DMODEL = 768;
static constexpr int ICH    = 1536;
static constexpr int NST    = 16;
static constexpr int MROWS  = 4096;   // B*S
static constexpr int NCH    = 64;     // scan chunks
static constexpr int CHS    = 32;     // steps per chunk
static constexpr int CSTR   = 2 * ICH * NST;   // 49152: per-chunk summary stride

typedef _Float16 f16;
typedef f16 f16x8 __attribute__((ext_vector_type(8)));
typedef f16 f16x4 __attribute__((ext_vector_type(4)));
typedef f16 f16x2 __attribute__((ext_vector_type(2)));
typedef float f32x4 __attribute__((ext_vector_type(4)));

#if __has_builtin(__builtin_amdgcn_exp2f)
#define EXP2F(x) __builtin_amdgcn_exp2f(x)
#else
#define EXP2F(x) exp2f(x)
#endif

typedef __attribute__((address_space(3))) void lds_void;
typedef const __attribute__((address_space(1))) void glb_void;

__device__ __forceinline__ void glds16(f16* l, const f16* g) {
    __builtin_amdgcn_global_load_lds((glb_void*)g, (lds_void*)l, 16, 0, 0);
}

__device__ __forceinline__ float silu_f(float x) {
    return x / (1.0f + __expf(-x));
}

// ---------------- cvt3: three fp32->fp16 conversions in one launch
__global__ __launch_bounds__(256) void cvt3(
    const float* __restrict__ s0, f16* __restrict__ d0, int n0,
    const float* __restrict__ s1, f16* __restrict__ d1, int n1,
    const float* __restrict__ s2, f16* __restrict__ d2)
{
    int i = (blockIdx.x * 256 + threadIdx.x) * 4;
    const float* s; f16* d;
    if (i < n0)            { s = s0 + i;            d = d0 + i; }
    else if (i < n0 + n1)  { s = s1 + (i - n0);     d = d1 + (i - n0); }
    else                   { s = s2 + (i - n0 - n1); d = d2 + (i - n0 - n1); }
    float4 v = *(const float4*)s;
    f16x4 o = { (f16)v.x, (f16)v.y, (f16)v.z, (f16)v.w };
    *(f16x4*)d = o;
}

// ---------------- K1: in_proj fp16 MFMA GEMM [4096,768] @ [3072,768]^T
// tile 128m x 64n (grid 32x48 = 1536 blocks), BK=64; waves 2x2, each 64m x 32n.
__global__ __launch_bounds__(256) void k1m(
    const f16* __restrict__ Xh,    // [4096][768]
    const f16* __restrict__ Wh,    // [3072][768]
    f16* __restrict__ hidden,      // [M][I]
    f16* __restrict__ sgate)       // [M][I] (silu applied)
{
    __shared__ __align__(16) f16 As[2][128 * 32];
    __shared__ __align__(16) f16 Bs[2][64 * 32];
    const int tid = threadIdx.x;
    const int lane = tid & 63, wave = tid >> 6;
    const int quad = lane >> 4, l16 = lane & 15;
    const int wm = wave & 1, wn = wave >> 1;   // wn in 0..1
    const int m0 = blockIdx.x * 128, n0 = blockIdx.y * 64;
    const int l_row = lane >> 2, l_c8 = (lane & 3) * 8;

    const f16* Ag = Xh + (size_t)(m0 + wave * 16 + l_row) * 768 + l_c8;
    const f16* Bg = Wh + (size_t)(n0 + wave * 16 + l_row) * 768 + l_c8;
    const int aLo = (wave * 16) * 32, aHi = (64 + wave * 16) * 32;
    const int bOff = (wave * 16) * 32;

    f32x4 acc[4][2] = {};
    for (int k0 = 0; k0 < 768; k0 += 64) {
        __syncthreads();
        glds16(&As[0][aLo], Ag + k0);
        glds16(&As[0][aHi], Ag + (size_t)64 * 768 + k0);
        glds16(&Bs[0][bOff], Bg + k0);
        glds16(&As[1][aLo], Ag + k0 + 32);
        glds16(&As[1][aHi], Ag + (size_t)64 * 768 + k0 + 32);
        glds16(&Bs[1][bOff], Bg + k0 + 32);
        __syncthreads();
        #pragma unroll
        for (int half = 0; half < 2; ++half) {
            f16x8 af[4], bf[2];
            #pragma unroll
            for (int mi = 0; mi < 4; ++mi)
                af[mi] = *(const f16x8*)&As[half][(wm * 64 + mi * 16 + l16) * 32 + quad * 8];
            #pragma unroll
            for (int ni = 0; ni < 2; ++ni)
                bf[ni] = *(const f16x8*)&Bs[half][(wn * 32 + ni * 16 + l16) * 32 + quad * 8];
            #pragma unroll
            for (int mi = 0; mi < 4; ++mi)
                #pragma unroll
                for (int ni = 0; ni < 2; ++ni)
                    acc[mi][ni] = __builtin_amdgcn_mfma_f32_16x16x32_f16(
                        af[mi], bf[ni], acc[mi][ni], 0, 0, 0);
        }
    }
    const bool isGate = (n0 >= ICH);
    f16* outp = isGate ? sgate : hidden;
    const int e0 = (isGate ? (n0 - ICH) : n0) + wn * 32 + l16;
    #pragma unroll
    for (int mi = 0; mi < 4; ++mi) {
        #pragma unroll
        for (int ni = 0; ni < 2; ++ni) {
            #pragma unroll
            for (int r = 0; r < 4; ++r) {
                int m = m0 + wm * 64 + mi * 16 + quad * 4 + r;
                int e = e0 + ni * 16;
                float v = acc[mi][ni][r];
                if (isGate) v = silu_f(v);
                outp[(size_t)m * ICH + e] = (f16)v;
            }
        }
    }
}

// ---------------- K2: causal depthwise conv (K=4) + bias + silu, f16 in/out
__global__ __launch_bounds__(256) void k2_conv(
    const f16* __restrict__ hidden,    // [M][I]
    const float* __restrict__ conv_w,  // [I][4]
    const float* __restrict__ conv_b,  // [I]
    f16* __restrict__ h)               // [M][I]
{
    int idx = blockIdx.x * 256 + threadIdx.x;      // over M * (I/4)
    int i4 = idx % 384;
    int m  = idx / 384;
    int s  = m & (S_LEN - 1);
    const f16* base = hidden + (size_t)m * ICH + i4 * 4;
    const int c0 = i4 * 4;
    float4 wa = *(const float4*)(conv_w + (c0 + 0) * 4);
    float4 wb = *(const float4*)(conv_w + (c0 + 1) * 4);
    float4 wc = *(const float4*)(conv_w + (c0 + 2) * 4);
    float4 wd = *(const float4*)(conv_w + (c0 + 3) * 4);
    float4 bv = *(const float4*)(conv_b + c0);
    f16x4 z = {};
    f16x4 x0 = *(const f16x4*)(base);
    f16x4 x1 = (s >= 1) ? *(const f16x4*)(base - ICH)     : z;
    f16x4 x2 = (s >= 2) ? *(const f16x4*)(base - 2 * ICH) : z;
    f16x4 x3 = (s >= 3) ? *(const f16x4*)(base - 3 * ICH) : z;
    float r0 = bv.x + wa.x * (float)x3[0] + wa.y * (float)x2[0] + wa.z * (float)x1[0] + wa.w * (float)x0[0];
    float r1 = bv.y + wb.x * (float)x3[1] + wb.y * (float)x2[1] + wb.z * (float)x1[1] + wb.w * (float)x0[1];
    float r2 = bv.z + wc.x * (float)x3[2] + wc.y * (float)x2[2] + wc.z * (float)x1[2] + wc.w * (float)x0[2];
    float r3 = bv.w + wd.x * (float)x3[3] + wd.y * (float)x2[3] + wd.z * (float)x1[3] + wd.w * (float)x0[3];
    f16x4 r = { (f16)silu_f(r0), (f16)silu_f(r1), (f16)silu_f(r2), (f16)silu_f(r3) };
    *(f16x4*)(h + (size_t)m * ICH + i4 * 4) = r;
}

// ---------------- K3: x_proj fp16 MFMA GEMM -> ssmp[m][e] (+=, atomics), ksplit x16
__global__ __launch_bounds__(256) void k3m(
    const f16* __restrict__ h,     // [M][I] f16
    const float* __restrict__ xw,  // [80][I] fp32
    float* __restrict__ ssmp)      // [M][80], pre-zeroed
{
    __shared__ __align__(16) f16 Ah[128 * 32];
    __shared__ __align__(16) f16 Bh[80 * 32];
    const int tid = threadIdx.x;
    const int lane = tid & 63, wave = tid >> 6;
    const int quad = lane >> 4, l16 = lane & 15;
    const int m0 = blockIdx.x * 128;
    const int kbeg = blockIdx.y * 96;
    const int l_row = lane >> 2, l_c8 = (lane & 3) * 8;

    const f16* Ag = h + (size_t)(m0 + wave * 32 + l_row) * ICH + l_c8;
    f16* As0 = Ah + (wave * 32) * 32;
    f16* As1 = Ah + (wave * 32 + 16) * 32;

    f32x4 acc[2][5] = {};
    for (int k0 = kbeg; k0 < kbeg + 96; k0 += 32) {
        __syncthreads();
        glds16(As0, Ag + k0);
        glds16(As1, Ag + (size_t)16 * ICH + k0);
        {   // stage B: 80 rows x 32 cols fp32 -> f16
            int c4 = (tid & 7) * 4;
            for (int r = tid >> 3; r < 80; r += 32) {
                float4 v = *(const float4*)(xw + (size_t)r * ICH + k0 + c4);
                f16x4 o = { (f16)v.x, (f16)v.y, (f16)v.z, (f16)v.w };
                *(f16x4*)&Bh[r * 32 + c4] = o;
            }
        }
        __syncthreads();
        f16x8 af[2], bf[5];
        #pragma unroll
        for (int mi = 0; mi < 2; ++mi)
            af[mi] = *(const f16x8*)&Ah[(wave * 32 + mi * 16 + l16) * 32 + quad * 8];
        #pragma unroll
        for (int j = 0; j < 5; ++j)
            bf[j] = *(const f16x8*)&Bh[(j * 16 + l16) * 32 + quad * 8];
        #pragma unroll
        for (int mi = 0; mi < 2; ++mi)
            #pragma unroll
            for (int j = 0; j < 5; ++j)
                acc[mi][j] = __builtin_amdgcn_mfma_f32_16x16x32_f16(
                    af[mi], bf[j], acc[mi][j], 0, 0, 0);
    }
    #pragma unroll
    for (int mi = 0; mi < 2; ++mi) {
        #pragma unroll
        for (int j = 0; j < 5; ++j) {
            #pragma unroll
            for (int r = 0; r < 4; ++r) {
                int m = m0 + wave * 32 + mi * 16 + quad * 4 + r;
                atomicAdd(ssmp + (size_t)m * 80 + j * 16 + l16, acc[mi][j][r]);
            }
        }
    }
}

// ---------------- K4: dt = softplus(ts @ dtw^T + b) via fp16 MFMA, K=48 padded to 64.
__global__ __launch_bounds__(256) void k4m(
    const float* __restrict__ ssmp,   // [M][80] (ts = cols 0..47)
    const float* __restrict__ dtw,    // [I][48]
    const float* __restrict__ dtb,    // [I]
    const float* __restrict__ alpha,  // [I]
    f16* __restrict__ dt)             // [M][I] f16
{
    __shared__ __align__(16) f16 As[128 * 72];   // [row][72] (64 K + 8 pad)
    __shared__ __align__(16) f16 Bs[128 * 72];
    const int tid = threadIdx.x;
    const int lane = tid & 63, wave = tid >> 6;
    const int quad = lane >> 4, l16 = lane & 15;
    const int wm = wave & 1, wn = wave >> 1;
    const int m0 = blockIdx.x * 128, n0 = blockIdx.y * 128;
    const int srow = tid >> 1;          // 0..127
    const int shalf = tid & 1;          // 0..1 -> cols [0,24) or [24,48)

    {   // stage A (ts) and B (dtw), cvt to fp16, zero-pad cols 48..63
        const float* sa = ssmp + (size_t)(m0 + srow) * 80 + shalf * 24;
        const float* sb = dtw + (size_t)(n0 + srow) * 48 + shalf * 24;
        f16* da = &As[srow * 72 + shalf * 24];
        f16* db = &Bs[srow * 72 + shalf * 24];
        #pragma unroll
        for (int j = 0; j < 6; ++j) {
            float4 va = *(const float4*)(sa + 4 * j);
            float4 vb = *(const float4*)(sb + 4 * j);
            f16x4 oa = { (f16)va.x, (f16)va.y, (f16)va.z, (f16)va.w };
            f16x4 ob = { (f16)vb.x, (f16)vb.y, (f16)vb.z, (f16)vb.w };
            *(f16x4*)(da + 4 * j) = oa;
            *(f16x4*)(db + 4 * j) = ob;
        }
        if (shalf) {
            f16x8 z = {};
            *(f16x8*)&As[srow * 72 + 48] = z;
            *(f16x8*)&As[srow * 72 + 56] = z;
            *(f16x8*)&Bs[srow * 72 + 48] = z;
            *(f16x8*)&Bs[srow * 72 + 56] = z;
        }
    }
    __syncthreads();

    f32x4 acc[4][4] = {};
    #pragma unroll
    for (int ks = 0; ks < 2; ++ks) {
        f16x8 af[4], bf[4];
        #pragma unroll
        for (int mi = 0; mi < 4; ++mi)
            af[mi] = *(const f16x8*)&As[(wm * 64 + mi * 16 + l16) * 72 + ks * 32 + quad * 8];
        #pragma unroll
        for (int ni = 0; ni < 4; ++ni)
            bf[ni] = *(const f16x8*)&Bs[(wn * 64 + ni * 16 + l16) * 72 + ks * 32 + quad * 8];
        #pragma unroll
        for (int mi = 0; mi < 4; ++mi)
            #pragma unroll
            for (int ni = 0; ni < 4; ++ni)
                acc[mi][ni] = __builtin_amdgcn_mfma_f32_16x16x32_f16(
                    af[mi], bf[ni], acc[mi][ni], 0, 0, 0);
    }

    #pragma unroll
    for (int ni = 0; ni < 4; ++ni) {
        int e = n0 + wn * 64 + ni * 16 + l16;
        float bias = dtb[e];
        float al = alpha[e];
        #pragma unroll
        for (int mi = 0; mi < 4; ++mi) {
            #pragma unroll
            for (int r = 0; r < 4; ++r) {
                int m = m0 + wm * 64 + mi * 16 + quad * 4 + r;
                float x = acc[mi][ni][r] + bias;
                float sp = (x > 20.0f) ? x : __logf(1.0f + __expf(x));
                if ((m & (S_LEN - 1)) == S_LEN - 1) sp *= al;
                dt[(size_t)m * ICH + e] = (f16)sp;
            }
        }
    }
}

// ---------------- K5a: per-chunk summary, LDS-staged dt/h/B; coalesced float4 P/Sf.
__global__ __launch_bounds__(256) void k5a_chunk(
    const f16* __restrict__ dt,      // [M][I] f16
    const f16* __restrict__ h,       // [M][I] f16
    const float* __restrict__ ssmp,  // [M][80]: B cols 48..63
    const float* __restrict__ A_log, // [I][16]
    float* __restrict__ PArr,        // [NCH][B*I*16]
    float* __restrict__ SfArr)       // [NCH][B*I*16]
{
    __shared__ float dts[CHS * 64];
    __shared__ float hs[CHS * 64];
    __shared__ float Bc[CHS][16];
    const int tid = threadIdx.x;
    const int n4 = tid & 3;
    const int il = tid >> 2;         // 0..63
    const int i0 = blockIdx.x * 64;
    const int i = i0 + il;
    const int c = blockIdx.y;
    const int b = blockIdx.z;
    const int s0 = c * CHS;
    const size_t row0 = (size_t)(b * S_LEN + s0) * ICH + i0;

    #pragma unroll
    for (int k = 0; k < (CHS * 64) / 512; ++k) {
        int idx = (tid + k * 256) * 2;
        size_t g_off = row0 + (size_t)(idx >> 6) * ICH + (idx & 63);
        f16x2 dv = *(const f16x2*)(dt + g_off);
        f16x2 hv = *(const f16x2*)(h + g_off);
        dts[idx] = (float)dv[0]; dts[idx + 1] = (float)dv[1];
        hs[idx]  = (float)hv[0]; hs[idx + 1]  = (float)hv[1];
    }
    if (tid < CHS * 4) {     // stage B rows: 32 t x 16 floats
        int t = tid >> 2, q = tid & 3;
        *(float4*)&Bc[t][q * 4] =
            *(const float4*)(ssmp + (size_t)(b * S_LEN + s0 + t) * 80 + 48 + q * 4);
    }

    const float L2E = 1.44269504088896f;
    float4 alv = *(const float4*)(A_log + i * NST + n4 * 4);
    float A[4] = { -__expf(alv.x) * L2E, -__expf(alv.y) * L2E,
                   -__expf(alv.z) * L2E, -__expf(alv.w) * L2E };
    float st[4] = {};
    float cdt = 0.f;
    __syncthreads();
    #pragma unroll 4
    for (int t = 0; t < CHS; ++t) {
        float dtv = dts[t * 64 + il];
        float hv  = hs[t * 64 + il];
        float4 Bv = *(const float4*)&Bc[t][n4 * 4];
        cdt += dtv;
        float x = dtv * hv;
        #pragma unroll
        for (int j = 0; j < 4; ++j) {
            float dA = EXP2F(A[j] * dtv);
            st[j] = fmaf(dA, st[j], x * (&Bv.x)[j]);
        }
    }
    size_t base = (size_t)c * CSTR + (size_t)(b * ICH + i) * NST + n4 * 4;
    float4 Pv = { EXP2F(A[0] * cdt), EXP2F(A[1] * cdt),
                  EXP2F(A[2] * cdt), EXP2F(A[3] * cdt) };   // telescoped prod dA
    float4 Sv = { st[0], st[1], st[2], st[3] };
    *(float4*)(PArr + base)  = Pv;
    *(float4*)(SfArr + base) = Sv;
}

// ---------------- K5b: combine chunk summaries into carry-in per chunk.
// Loads are independent of the carry chain: batch all loads, then serial scan.
__global__ __launch_bounds__(256) void k5b_carry(
    const float* PArr,       // [NCH][49152]
    const float* __restrict__ SfArr,
    float* CIn)              // aliases PArr
{
    int idx = blockIdx.x * 256 + threadIdx.x;   // over B*I*16 = 49152
    float p[NCH], s[NCH];
    #pragma unroll
    for (int c = 0; c < NCH; ++c) {
        size_t a = (size_t)c * CSTR + idx;
        p[c] = PArr[a];
        s[c] = SfArr[a];
    }
    float carry = 0.f;
    #pragma unroll
    for (int c = 0; c < NCH; ++c) {
        CIn[(size_t)c * CSTR + idx] = carry;
        carry = fmaf(p[c], carry, s[c]);
    }
}

// ---------------- K5c: replay chunk with carry-in, emit y fp16; LDS-staged inputs
__global__ __launch_bounds__(256) void k5c_emit(
    const f16* __restrict__ dt,      // [M][I] f16
    const f16* __restrict__ h,       // [M][I] f16
    const f16* __restrict__ sgate,   // [M][I] f16
    const float* __restrict__ ssmp,  // [M][80]: B 48..63, C 64..79
    const float* __restrict__ A_log, // [I][16]
    const float* __restrict__ Dp,    // [I]
    const float* __restrict__ fg,    // [I]
    const float* __restrict__ CIn,   // [NCH][49152]
    f16* __restrict__ yh)            // [M][I] fp16
{
    __shared__ float dts[CHS * 64];
    __shared__ float hs[CHS * 64];
    __shared__ float gs[CHS * 64];
    __shared__ float BC[CHS][32];    // [t][0..15]=B, [16..31]=C
    const int tid = threadIdx.x;
    const int n4 = tid & 3;
    const int il = tid >> 2;
    const int i0 = blockIdx.x * 64;
    const int i = i0 + il;
    const int c = blockIdx.y;
    const int b = blockIdx.z;
    const int s0 = c * CHS;
    const size_t row0 = (size_t)(b * S_LEN + s0) * ICH + i0;

    #pragma unroll
    for (int k = 0; k < (CHS * 64) / 512; ++k) {
        int idx = (tid + k * 256) * 2;
        size_t g_off = row0 + (size_t)(idx >> 6) * ICH + (idx & 63);
        f16x2 dv = *(const f16x2*)(dt + g_off);
        f16x2 v = *(const f16x2*)(h + g_off);
        f16x2 w = *(const f16x2*)(sgate + g_off);
        dts[idx] = (float)dv[0]; dts[idx + 1] = (float)dv[1];
        hs[idx] = (float)v[0]; hs[idx + 1] = (float)v[1];
        gs[idx] = (float)w[0]; gs[idx + 1] = (float)w[1];
    }
    {   // stage B+C rows: 32 t x 32 floats = 256 float4
        int t = tid >> 3, q = tid & 7;
        *(float4*)&BC[t][q * 4] =
            *(const float4*)(ssmp + (size_t)(b * S_LEN + s0 + t) * 80 + 48 + q * 4);
    }

    const float L2E = 1.44269504088896f;
    float4 alv = *(const float4*)(A_log + i * NST + n4 * 4);
    float A[4] = { -__expf(alv.x) * L2E, -__expf(alv.y) * L2E,
                   -__expf(alv.z) * L2E, -__expf(alv.w) * L2E };
    const float Dv = Dp[i];
    const float fgv = fg[i];
    float4 civ = *(const float4*)(CIn + (size_t)c * CSTR + (size_t)(b * ICH + i) * NST + n4 * 4);
    float st[4] = { civ.x, civ.y, civ.z, civ.w };
    f16* yout = yh + row0 + il;
    const bool last_chunk = (c == NCH - 1);
    __syncthreads();
    #pragma unroll 4
    for (int t = 0; t < CHS; ++t) {
        float dtv = dts[t * 64 + il];
        float hv  = hs[t * 64 + il];
        float4 Bv = *(const float4*)&BC[t][n4 * 4];
        float4 Cv = *(const float4*)&BC[t][16 + n4 * 4];
        float x = dtv * hv;
        float yp = 0.f;
        #pragma unroll
        for (int j = 0; j < 4; ++j) {
            float dA = EXP2F(A[j] * dtv);
            st[j] = fmaf(dA, st[j], x * (&Bv.x)[j]);
            yp = fmaf(st[j], (&Cv.x)[j], yp);
        }
        yp += __shfl_xor(yp, 1, 4);
        yp += __shfl_xor(yp, 2, 4);
        if (n4 == 0) {
            float yv = fmaf(hv, Dv, yp) * gs[t * 64 + il];
            if (last_chunk && t == CHS - 1) yv *= fgv;
            yout[(size_t)t * ICH] = (f16)yv;
        }
    }
}

// ---------------- K6: out_proj fp16 MFMA GEMM [4096,1536] @ [768,1536]^T
// tile 128m x 64n (grid 32x12 = 384 blocks), BK=64; waves 2x2, each 64m x 32n.
__global__ __launch_bounds__(256) void k6m(
    const f16* __restrict__ Yh,    // [4096][1536]
    const f16* __restrict__ Wh,    // [768][1536]
    float* __restrict__ out)       // [M][768]
{
    __shared__ __align__(16) f16 As[2][128 * 32];
    __shared__ __align__(16) f16 Bs[2][64 * 32];
    const int tid = threadIdx.x;
    const int lane = tid & 63, wave = tid >> 6;
    const int quad = lane >> 4, l16 = lane & 15;
    const int wm = wave & 1, wn = wave >> 1;   // wn in 0..1
    const int m0 = blockIdx.x * 128, n0 = blockIdx.y * 64;
    const int l_row = lane >> 2, l_c8 = (lane & 3) * 8;

    const f16* Ag = Yh + (size_t)(m0 + wave * 16 + l_row) * ICH + l_c8;
    const f16* Bg = Wh + (size_t)(n0 + wave * 16 + l_row) * ICH + l_c8;
    const int aLo = (wave * 16) * 32, aHi = (64 + wave * 16) * 32;
    const int bOff = (wave * 16) * 32;

    f32x4 acc[4][2] = {};
    for (int k0 = 0; k0 < ICH; k0 += 64) {
        __syncthreads();
        glds16(&As[0][aLo], Ag + k0);
        glds16(&As[0][aHi], Ag + (size_t)64 * ICH + k0);
        glds16(&Bs[0][bOff], Bg + k0);
        glds16(&As[1][aLo], Ag + k0 + 32);
        glds16(&As[1][aHi], Ag + (size_t)64 * ICH + k0 + 32);
        glds16(&Bs[1][bOff], Bg + k0 + 32);
        __syncthreads();
        #pragma unroll
        for (int half = 0; half < 2; ++half) {
            f16x8 af[4], bf[2];
            #pragma unroll
            for (int mi = 0; mi < 4; ++mi)
                af[mi] = *(const f16x8*)&As[half][(wm * 64 + mi * 16 + l16) * 32 + quad * 8];
            #pragma unroll
            for (int ni = 0; ni < 2; ++ni)
                bf[ni] = *(const f16x8*)&Bs[half][(wn * 32 + ni * 16 + l16) * 32 + quad * 8];
            #pragma unroll
            for (int mi = 0; mi < 4; ++mi)
                #pragma unroll
                for (int ni = 0; ni < 2; ++ni)
                    acc[mi][ni] = __builtin_amdgcn_mfma_f32_16x16x32_f16(
                        af[mi], bf[ni], acc[mi][ni], 0, 0, 0);
        }
    }
    #pragma unroll
    for (int mi = 0; mi < 4; ++mi) {
        #pragma unroll
        for (int ni = 0; ni < 2; ++ni) {
            #pragma unroll
            for (int r = 0; r < 4; ++r) {
                int m = m0 + wm * 64 + mi * 16 + quad * 4 + r;
                int d = n0 + wn * 32 + ni * 16 + l16;
                out[(size_t)m * DMODEL + d] = acc[mi][ni][r];
            }
        }
    }
}

extern "C" void kernel_launch(void* const* d_in, const int* in_sizes, int n_in,
                              void* d_out, int out_size, void* d_ws, size_t ws_size,
                              hipStream_t stream) {
    const float* X     = (const float*)d_in[0];
    const float* W1    = (const float*)d_in[1];
    const float* CW    = (const float*)d_in[2];
    const float* CB    = (const float*)d_in[3];
    const float* XW    = (const float*)d_in[4];
    const float* DTW   = (const float*)d_in[5];
    const float* DTB   = (const float*)d_in[6];
    const float* ALOG  = (const float*)d_in[7];
    const float* DD    = (const float*)d_in[8];
    const float* OW    = (const float*)d_in[9];
    const float* ALPHA = (const float*)d_in[10];
    const float* FG    = (const float*)d_in[11];
    float* out = (float*)d_out;

    const size_t NBI = (size_t)MROWS * ICH;         // 6,291,456
    f16* hidden_h = (f16*)d_ws;                     // 12.58 MB
    f16* sgate_h  = hidden_h + NBI;
    f16* h_h      = sgate_h + NBI;
    f16* dt_h     = h_h + NBI;                      // f16
    float* ssmp   = (float*)(dt_h + NBI);           // 1.31 MB
    f16* Xh       = (f16*)(ssmp + (size_t)MROWS * 80);
    f16* W1h      = Xh + (size_t)MROWS * DMODEL;
    f16* OWh      = W1h + (size_t)2 * ICH * DMODEL;
    float* SfA    = (float*)(OWh + (size_t)DMODEL * ICH);   // 12.58 MB
    // overlays: P/CIn on hidden_h (dead after k2); yh on Sf (dead after k5b)
    float* PArr = (float*)hidden_h;                 // NCH*CSTR floats = 12.58 MB exact
    float* CIn  = PArr;
    f16* yh     = (f16*)SfA;                        // NBI f16 = 12.58 MB exact

    const int nX = MROWS * DMODEL, nW1 = 2 * ICH * DMODEL, nOW = DMODEL * ICH;
    hipMemsetAsync(ssmp, 0, (size_t)MROWS * 80 * sizeof(float), stream);
    cvt3<<<dim3((nX + nW1 + nOW) / 1024), 256, 0, stream>>>(X, Xh, nX, W1, W1h, nW1, OW, OWh);
    k1m<<<dim3(32, 48), 256, 0, stream>>>(Xh, W1h, hidden_h, sgate_h);
    k2_conv<<<dim3((MROWS * 384) / 256), 256, 0, stream>>>(hidden_h, CW, CB, h_h);
    k3m<<<dim3(32, 16), 256, 0, stream>>>(h_h, XW, ssmp);
    k4m<<<dim3(32, 12), 256, 0, stream>>>(ssmp, DTW, DTB, ALPHA, dt_h);
    k5a_chunk<<<dim3(24, NCH, 2), 256, 0, stream>>>(dt_h, h_h, ssmp, ALOG, PArr, SfA);
    k5b_carry<<<dim3(192), 256, 0, stream>>>(PArr, SfA, CIn);
    k5c_emit<<<dim3(24, NCH, 2), 256, 0, stream>>>(dt_h, h_h, sgate_h, ssmp, ALOG, DD, FG, CIn, yh);
    k6m<<<dim3(32, 12), 256, 0, stream>>>(yh, OWh, out);
}